// Round 3
// baseline (141.102 us; speedup 1.0000x reference)
//
#include <hip/hip_runtime.h>

// Batched 14-qubit statevector simulator, v3.
// v2 -> v3: pin register budget with amdgpu_waves_per_eu(2,2). v2 spilled the
// 32-amplitude register coset to scratch (106 MB HBM traffic/dispatch, VGPR
// capped at 128 by the allocator's occupancy heuristic). LDS caps us at
// 1 block/CU (8 waves) regardless, so a 256-VGPR budget costs nothing.
// - State (2^14 complex64 = 128 KB) lives in LDS per block (1 sample/block).
// - Encoding + layer-1 1q gates folded into a product state built in registers.
// - Layers 2 and 3: gates grouped 5/5/4 wires per pass; each thread pulls one
//   coset of 32 (or 2x16) amplitudes into registers, applies the group's 2x2
//   gates in-register, writes back. CNOTs are compile-time GF(2) index algebra.
// - Readout via in-register 32-point Walsh-Hadamard transform.

#define NQ 14
#define NS (1 << NQ)
#define NT 512
#define NLAYERS 3

// ---------------- compile-time GF(2) schedule ----------------
struct Sched {
    unsigned m2[NQ], r2[NQ];   // masks/rows for layer-2 gates (after 1 CNOT ring)
    unsigned m3[NQ], r3[NQ];   // for layer-3 gates (after 2 rings)
    unsigned frow[NQ];         // readout rows (after 3 rings)
};

constexpr Sched make_sched() {
    Sched s{};
    unsigned c[NQ] = {}, r[NQ] = {};
    for (int w = 0; w < NQ; ++w) { c[w] = 1u << (NQ - 1 - w); r[w] = 1u << (NQ - 1 - w); }
    for (int ring = 0; ring < 3; ++ring) {
        // CNOT(w, w+1) for w=0..12, then CNOT(13, 0): cols[c]^=cols[t]; rows[t]^=rows[c]
        for (int w = 0; w < NQ - 1; ++w) { c[w] ^= c[w + 1]; r[w + 1] ^= r[w]; }
        c[NQ - 1] ^= c[0]; r[0] ^= r[NQ - 1];
        if (ring == 0) for (int w = 0; w < NQ; ++w) { s.m2[w] = c[w]; s.r2[w] = r[w]; }
        if (ring == 1) for (int w = 0; w < NQ; ++w) { s.m3[w] = c[w]; s.r3[w] = r[w]; }
        if (ring == 2) for (int w = 0; w < NQ; ++w) { s.frow[w] = r[w]; }
    }
    return s;
}
constexpr Sched S = make_sched();

struct Meta {
    unsigned mask[5];
    unsigned row[5];
    unsigned lut[32];   // lut[j] = XOR of mask[i] over set bits i of j
    unsigned npiv;      // non-pivot bit mask (complement basis positions)
    int K;              // wires in this pass (5 or 4)
    int g0;             // base index into gate-matrix table
};

constexpr Meta mkpass(const unsigned* m, const unsigned* r, int w0, int K, int g0base) {
    Meta p{};
    p.K = K; p.g0 = g0base + w0;
    for (int i = 0; i < K; ++i) { p.mask[i] = m[w0 + i]; p.row[i] = r[w0 + i]; }
    // Gaussian elimination, preferring HIGH pivot bits (so non-pivots — the
    // per-thread rep bits — occupy low bits => good LDS bank spread).
    unsigned red[5] = {}, pivbit[5] = {}, pivs = 0;
    for (int i = 0; i < K; ++i) {
        unsigned v = p.mask[i];
        for (int j = 0; j < i; ++j) if (v & pivbit[j]) v ^= red[j];
        unsigned hb = 0;
        for (int b = 13; b >= 0; --b) if ((v >> b) & 1u) { hb = 1u << b; break; }
        red[i] = v; pivbit[i] = hb; pivs |= hb;
    }
    p.npiv = (~pivs) & 0x3FFFu;
    for (int j = 0; j < (1 << K); ++j) {
        unsigned x = 0;
        for (int i = 0; i < K; ++i) if ((j >> i) & 1) x ^= p.mask[i];
        p.lut[j] = x;
    }
    return p;
}

constexpr Meta PM[6] = {
    mkpass(S.m2, S.r2, 0, 5, 0),  mkpass(S.m2, S.r2, 5, 5, 0),  mkpass(S.m2, S.r2, 10, 4, 0),
    mkpass(S.m3, S.r3, 0, 5, 14), mkpass(S.m3, S.r3, 5, 5, 14), mkpass(S.m3, S.r3, 10, 4, 14),
};
static_assert(__builtin_popcount(PM[0].npiv) == 9, "GE failed p0");
static_assert(__builtin_popcount(PM[2].npiv) == 10, "GE failed p2");
static_assert(__builtin_popcount(PM[5].npiv) == 10, "GE failed p5");

// ---------------- complex helpers ----------------
struct c32 { float x, y; };
__device__ __forceinline__ c32 cmul(c32 a, c32 b) {
    return c32{ a.x * b.x - a.y * b.y, a.x * b.y + a.y * b.x };
}
__device__ __forceinline__ c32 cadd(c32 a, c32 b) { return c32{ a.x + b.x, a.y + b.y }; }
__device__ __forceinline__ float2 cmulf(float2 a, float2 b) {
    return make_float2(a.x * b.x - a.y * b.y, a.x * b.y + a.y * b.x);
}

struct M2x2 { c32 a, b, c, d; };
__device__ __forceinline__ M2x2 mmul(M2x2 X, M2x2 Y) {
    M2x2 o;
    o.a = cadd(cmul(X.a, Y.a), cmul(X.b, Y.c));
    o.b = cadd(cmul(X.a, Y.b), cmul(X.b, Y.d));
    o.c = cadd(cmul(X.c, Y.a), cmul(X.d, Y.c));
    o.d = cadd(cmul(X.c, Y.b), cmul(X.d, Y.d));
    return o;
}
__device__ __forceinline__ M2x2 mRX(float c, float s) { return M2x2{ {c,0.f},{0.f,-s},{0.f,-s},{c,0.f} }; }
__device__ __forceinline__ M2x2 mRY(float c, float s) { return M2x2{ {c,0.f},{-s,0.f},{s,0.f},{c,0.f} }; }
__device__ __forceinline__ M2x2 mRZ(float c, float s) { return M2x2{ {c,-s},{0.f,0.f},{0.f,0.f},{c,s} }; }

// ---------------- one grouped gate pass ----------------
template<int P>
__device__ __forceinline__ void do_pass(float2* st, const float4* gm4, int tid) {
    constexpr Meta pm = PM[P];
    constexpr int K = pm.K;
    constexpr int NSLOT = 1 << K;
    constexpr int NCS = (K == 5) ? 1 : 2;

    #pragma unroll
    for (int cs = 0; cs < NCS; ++cs) {
        unsigned idx = (unsigned)tid + (unsigned)(cs << 9);
        // coset representative: deposit idx bits into non-pivot positions
        unsigned rep = 0;
        #pragma unroll
        for (int bb = 0; bb < 14; ++bb)
            if ((pm.npiv >> bb) & 1u)
                rep |= ((idx >> __builtin_popcount(pm.npiv & ((1u << bb) - 1))) & 1u) << bb;
        // lane-dependent offset within the coset (bank spread); linear in idx
        unsigned lt = 0;
        #pragma unroll
        for (int i = 0; i < K; ++i) lt ^= ((idx >> i) & 1u) ? pm.mask[i] : 0u;
        const unsigned repf = rep ^ lt;
        // role-parity per gate: selects normal vs swapped matrix variant
        unsigned sel[5];
        #pragma unroll
        for (int i = 0; i < K; ++i) sel[i] = __popc(repf & pm.row[i]) & 1u;

        float2 e[NSLOT];
        #pragma unroll
        for (int j = 0; j < NSLOT; ++j) e[j] = st[repf ^ pm.lut[j]];

        #pragma unroll
        for (int w = 0; w < K; ++w) {
            const float4* mp = gm4 + (((unsigned)(pm.g0 + w) * 2u + sel[w]) * 2u);
            const float4 R0 = mp[0];   // (A.re, A.im, B.re, B.im)
            const float4 R1 = mp[1];   // (C.re, C.im, D.re, D.im)
            #pragma unroll
            for (int t = 0; t < NSLOT / 2; ++t) {
                const int j  = ((t >> w) << (w + 1)) | (t & ((1 << w) - 1));
                const int j2 = j | (1 << w);
                const float2 x = e[j], y = e[j2];
                e[j]  = make_float2(R0.x * x.x - R0.y * x.y + R0.z * y.x - R0.w * y.y,
                                    R0.x * x.y + R0.y * x.x + R0.z * y.y + R0.w * y.x);
                e[j2] = make_float2(R1.x * x.x - R1.y * x.y + R1.z * y.x - R1.w * y.y,
                                    R1.x * x.y + R1.y * x.x + R1.z * y.y + R1.w * y.x);
            }
        }
        #pragma unroll
        for (int j = 0; j < NSLOT; ++j) st[repf ^ pm.lut[j]] = e[j];
    }
}

__global__ __launch_bounds__(NT)
__attribute__((amdgpu_waves_per_eu(2, 2)))   // LDS caps us at 1 block/CU anyway:
                                             // allow the full 256-VGPR budget so
                                             // the 32-amplitude coset never spills
void qsim_kernel(const float* __restrict__ z, const float* __restrict__ th,
                 float* __restrict__ out)
{
    extern __shared__ float2 st[];            // 16384 x 8 B state
    __shared__ float4 gm4[28 * 4];            // [gate 0..27][variant 0/1][2x float4]
    __shared__ float2 vtab[NQ][2];            // per-wire (encoding x layer-1) |psi_w>
    __shared__ float  red[NT / 64][NQ];

    const int bq  = blockIdx.x;
    const int tid = threadIdx.x;

    // ---- metadata: fused gate matrices + per-wire product vectors ----
    if (tid < 28) {
        const int rd = tid / 14, w = tid % 14, l = rd + 1;   // theta layers 1,2
        const float* tp = th + (l * NQ + w) * 3;
        float s0, c0, s1, c1, s2, c2;
        __sincosf(0.5f * tp[0], &s0, &c0);
        __sincosf(0.5f * tp[1], &s1, &c1);
        __sincosf(0.5f * tp[2], &s2, &c2);
        const M2x2 G = mmul(mRZ(c2, s2), mmul(mRY(c1, s1), mRX(c0, s0)));
        gm4[tid * 4 + 0] = make_float4(G.a.x, G.a.y, G.b.x, G.b.y);
        gm4[tid * 4 + 1] = make_float4(G.c.x, G.c.y, G.d.x, G.d.y);
        gm4[tid * 4 + 2] = make_float4(G.d.x, G.d.y, G.c.x, G.c.y);  // swapped variant
        gm4[tid * 4 + 3] = make_float4(G.b.x, G.b.y, G.a.x, G.a.y);
    } else if (tid >= 32 && tid < 32 + NQ) {
        const int w = tid - 32;
        const float zt = z[bq * NQ + w];
        float sz_, cz_; __sincosf(0.5f * zt, &sz_, &cz_);
        // (RZ(z)*RY(z)) |0> = (cos*e^{-iz/2}, sin*e^{+iz/2})
        const c32 a0{ cz_ * cz_, -cz_ * sz_ }, b0{ sz_ * cz_, sz_ * sz_ };
        const float* tp = th + (0 * NQ + w) * 3;
        float s0, c0, s1, c1, s2, c2;
        __sincosf(0.5f * tp[0], &s0, &c0);
        __sincosf(0.5f * tp[1], &s1, &c1);
        __sincosf(0.5f * tp[2], &s2, &c2);
        const M2x2 G = mmul(mRZ(c2, s2), mmul(mRY(c1, s1), mRX(c0, s0)));
        const c32 v0 = cadd(cmul(G.a, a0), cmul(G.b, b0));
        const c32 v1 = cadd(cmul(G.c, a0), cmul(G.d, b0));
        vtab[w][0] = make_float2(v0.x, v0.y);
        vtab[w][1] = make_float2(v1.x, v1.y);
    }
    __syncthreads();

    // ---- init: product state (encoding + layer-1 folded), strided layout ----
    {
        // y = tid + j*512 ; y bit p (p<9) from tid => wire 13-p ; j bit b => wire 4-b
        float2 pf = vtab[13][tid & 1];
        #pragma unroll
        for (int p = 1; p < 9; ++p) pf = cmulf(pf, vtab[13 - p][(tid >> p) & 1]);
        float2 e[32];
        e[0] = pf;
        #pragma unroll
        for (int bb = 0; bb < 5; ++bb) {
            const float2 v0 = vtab[4 - bb][0], v1 = vtab[4 - bb][1];
            #pragma unroll
            for (int t = 0; t < (1 << bb); ++t) {
                const float2 base = e[t];
                e[t + (1 << bb)] = cmulf(base, v1);
                e[t] = cmulf(base, v0);
            }
        }
        #pragma unroll
        for (int j = 0; j < 32; ++j) st[tid + (j << 9)] = e[j];
    }
    __syncthreads();

    // ---- 6 grouped gate passes (layers 2 and 3) ----
    do_pass<0>(st, gm4, tid); __syncthreads();
    do_pass<1>(st, gm4, tid); __syncthreads();
    do_pass<2>(st, gm4, tid); __syncthreads();
    do_pass<3>(st, gm4, tid); __syncthreads();
    do_pass<4>(st, gm4, tid); __syncthreads();
    do_pass<5>(st, gm4, tid); __syncthreads();

    // ---- readout: |amp|^2, in-register WHT over the 5 high bits ----
    float W[32];
    #pragma unroll
    for (int j = 0; j < 32; ++j) {
        const float2 a = st[tid + (j << 9)];
        W[j] = a.x * a.x + a.y * a.y;
    }
    #pragma unroll
    for (int bb = 0; bb < 5; ++bb) {
        #pragma unroll
        for (int t = 0; t < 16; ++t) {
            const int j  = ((t >> bb) << (bb + 1)) | (t & ((1 << bb) - 1));
            const int j2 = j | (1 << bb);
            const float u = W[j], v = W[j2];
            W[j] = u + v; W[j2] = u - v;
        }
    }
    float ev[NQ];
    #pragma unroll
    for (int w = 0; w < NQ; ++w) {
        const float val = W[S.frow[w] >> 9];
        ev[w] = (__popc((unsigned)tid & (S.frow[w] & 0x1FFu)) & 1) ? -val : val;
    }
    const int lane = tid & 63, wv = tid >> 6;
    #pragma unroll
    for (int w = 0; w < NQ; ++w) {
        float v = ev[w];
        #pragma unroll
        for (int off = 32; off > 0; off >>= 1) v += __shfl_down(v, off, 64);
        if (lane == 0) red[wv][w] = v;
    }
    __syncthreads();
    if (tid < NQ) {
        float v = 0.f;
        #pragma unroll
        for (int i = 0; i < NT / 64; ++i) v += red[i][tid];
        out[bq * NQ + tid] = v;
    }
}

extern "C" void kernel_launch(void* const* d_in, const int* in_sizes, int n_in,
                              void* d_out, int out_size, void* d_ws, size_t ws_size,
                              hipStream_t stream)
{
    (void)n_in; (void)out_size; (void)d_ws; (void)ws_size;
    const float* z  = (const float*)d_in[0];   // (256, 14) float32
    const float* th = (const float*)d_in[1];   // (3, 14, 3) float32
    float* out = (float*)d_out;                // (256, 14) float32

    const int B = in_sizes[0] / NQ;

    hipFuncSetAttribute(reinterpret_cast<const void*>(qsim_kernel),
                        hipFuncAttributeMaxDynamicSharedMemorySize, NS * 8);

    qsim_kernel<<<dim3(B), dim3(NT), NS * 8, stream>>>(z, th, out);
}

// Round 7
// 107.791 us; speedup vs baseline: 1.3090x; 1.3090x over previous
//
#include <hip/hip_runtime.h>

// Batched 14-qubit statevector simulator, v4.
// v3 -> v4: v2/v3 spilled the 32-amplitude register coset to scratch
// (VGPR allocator targets a 128-reg budget; e[32] float2 = 64 VGPRs pushed
// peak demand past it; waves_per_eu attr was ignored -> 149 MB/dispatch of
// scratch traffic dominated runtime). Fix: regroup gate passes K=5,5,4 ->
// K=4,4,3,3 (e[16] = 32 VGPRs, peak live ~70 regs, fits any budget), and
// split the init product tree the same way. Gate-application count is
// invariant under grouping; only pass count rises 6 -> 8.
// - State (2^14 complex64 = 128 KB) lives in LDS per block (1 sample/block).
// - Encoding + layer-1 1q gates folded into a product state built in registers.
// - CNOTs are compile-time GF(2) index algebra (zero data movement).
// - Readout via in-register 32-point Walsh-Hadamard transform.

#define NQ 14
#define NS (1 << NQ)
#define NT 512
#define NLAYERS 3

// ---------------- compile-time GF(2) schedule ----------------
struct Sched {
    unsigned m2[NQ], r2[NQ];   // masks/rows for layer-2 gates (after 1 CNOT ring)
    unsigned m3[NQ], r3[NQ];   // for layer-3 gates (after 2 rings)
    unsigned frow[NQ];         // readout rows (after 3 rings)
};

constexpr Sched make_sched() {
    Sched s{};
    unsigned c[NQ] = {}, r[NQ] = {};
    for (int w = 0; w < NQ; ++w) { c[w] = 1u << (NQ - 1 - w); r[w] = 1u << (NQ - 1 - w); }
    for (int ring = 0; ring < 3; ++ring) {
        // CNOT(w, w+1) for w=0..12, then CNOT(13, 0): cols[c]^=cols[t]; rows[t]^=rows[c]
        for (int w = 0; w < NQ - 1; ++w) { c[w] ^= c[w + 1]; r[w + 1] ^= r[w]; }
        c[NQ - 1] ^= c[0]; r[0] ^= r[NQ - 1];
        if (ring == 0) for (int w = 0; w < NQ; ++w) { s.m2[w] = c[w]; s.r2[w] = r[w]; }
        if (ring == 1) for (int w = 0; w < NQ; ++w) { s.m3[w] = c[w]; s.r3[w] = r[w]; }
        if (ring == 2) for (int w = 0; w < NQ; ++w) { s.frow[w] = r[w]; }
    }
    return s;
}
constexpr Sched S = make_sched();

struct Meta {
    unsigned mask[4];
    unsigned row[4];
    unsigned lut[16];   // lut[j] = XOR of mask[i] over set bits i of j
    unsigned npiv;      // non-pivot bit mask (complement basis positions)
    int K;              // wires in this pass (4 or 3)
    int g0;             // base index into gate-matrix table
};

constexpr Meta mkpass(const unsigned* m, const unsigned* r, int w0, int K, int g0base) {
    Meta p{};
    p.K = K; p.g0 = g0base + w0;
    for (int i = 0; i < K; ++i) { p.mask[i] = m[w0 + i]; p.row[i] = r[w0 + i]; }
    // Gaussian elimination, preferring HIGH pivot bits (so non-pivots — the
    // per-thread rep bits — occupy low bits => good LDS bank spread).
    unsigned red[4] = {}, pivbit[4] = {}, pivs = 0;
    for (int i = 0; i < K; ++i) {
        unsigned v = p.mask[i];
        for (int j = 0; j < i; ++j) if (v & pivbit[j]) v ^= red[j];
        unsigned hb = 0;
        for (int b = 13; b >= 0; --b) if ((v >> b) & 1u) { hb = 1u << b; break; }
        red[i] = v; pivbit[i] = hb; pivs |= hb;
    }
    p.npiv = (~pivs) & 0x3FFFu;
    for (int j = 0; j < (1 << K); ++j) {
        unsigned x = 0;
        for (int i = 0; i < K; ++i) if ((j >> i) & 1) x ^= p.mask[i];
        p.lut[j] = x;
    }
    return p;
}

constexpr Meta PM[8] = {
    mkpass(S.m2, S.r2, 0, 4, 0),  mkpass(S.m2, S.r2, 4, 4, 0),
    mkpass(S.m2, S.r2, 8, 3, 0),  mkpass(S.m2, S.r2, 11, 3, 0),
    mkpass(S.m3, S.r3, 0, 4, 14), mkpass(S.m3, S.r3, 4, 4, 14),
    mkpass(S.m3, S.r3, 8, 3, 14), mkpass(S.m3, S.r3, 11, 3, 14),
};
static_assert(__builtin_popcount(PM[0].npiv) == 10, "GE failed p0");
static_assert(__builtin_popcount(PM[2].npiv) == 11, "GE failed p2");
static_assert(__builtin_popcount(PM[5].npiv) == 10, "GE failed p5");
static_assert(__builtin_popcount(PM[7].npiv) == 11, "GE failed p7");

// ---------------- complex helpers ----------------
struct c32 { float x, y; };
__device__ __forceinline__ c32 cmul(c32 a, c32 b) {
    return c32{ a.x * b.x - a.y * b.y, a.x * b.y + a.y * b.x };
}
__device__ __forceinline__ c32 cadd(c32 a, c32 b) { return c32{ a.x + b.x, a.y + b.y }; }
__device__ __forceinline__ float2 cmulf(float2 a, float2 b) {
    return make_float2(a.x * b.x - a.y * b.y, a.x * b.y + a.y * b.x);
}

struct M2x2 { c32 a, b, c, d; };
__device__ __forceinline__ M2x2 mmul(M2x2 X, M2x2 Y) {
    M2x2 o;
    o.a = cadd(cmul(X.a, Y.a), cmul(X.b, Y.c));
    o.b = cadd(cmul(X.a, Y.b), cmul(X.b, Y.d));
    o.c = cadd(cmul(X.c, Y.a), cmul(X.d, Y.c));
    o.d = cadd(cmul(X.c, Y.b), cmul(X.d, Y.d));
    return o;
}
__device__ __forceinline__ M2x2 mRX(float c, float s) { return M2x2{ {c,0.f},{0.f,-s},{0.f,-s},{c,0.f} }; }
__device__ __forceinline__ M2x2 mRY(float c, float s) { return M2x2{ {c,0.f},{-s,0.f},{s,0.f},{c,0.f} }; }
__device__ __forceinline__ M2x2 mRZ(float c, float s) { return M2x2{ {c,-s},{0.f,0.f},{0.f,0.f},{c,s} }; }

// ---------------- one grouped gate pass ----------------
template<int P>
__device__ __forceinline__ void do_pass(float2* st, const float4* gm4, int tid) {
    constexpr Meta pm = PM[P];
    constexpr int K = pm.K;
    constexpr int NSLOT = 1 << K;         // 16 or 8
    constexpr int NCS = 1 << (5 - K);     // cosets per thread: 2 or 4

    #pragma unroll
    for (int cs = 0; cs < NCS; ++cs) {
        unsigned idx = (unsigned)tid + (unsigned)(cs << 9);
        // coset representative: deposit idx bits into non-pivot positions
        unsigned rep = 0;
        #pragma unroll
        for (int bb = 0; bb < 14; ++bb)
            if ((pm.npiv >> bb) & 1u)
                rep |= ((idx >> __builtin_popcount(pm.npiv & ((1u << bb) - 1))) & 1u) << bb;
        // lane-dependent offset within the coset (bank spread); linear in idx
        unsigned lt = 0;
        #pragma unroll
        for (int i = 0; i < K; ++i) lt ^= ((idx >> i) & 1u) ? pm.mask[i] : 0u;
        const unsigned repf = rep ^ lt;
        // role-parity per gate: selects normal vs swapped matrix variant
        unsigned sel[4];
        #pragma unroll
        for (int i = 0; i < K; ++i) sel[i] = __popc(repf & pm.row[i]) & 1u;

        float2 e[NSLOT];
        #pragma unroll
        for (int j = 0; j < NSLOT; ++j) e[j] = st[repf ^ pm.lut[j]];

        #pragma unroll
        for (int w = 0; w < K; ++w) {
            const float4* mp = gm4 + (((unsigned)(pm.g0 + w) * 2u + sel[w]) * 2u);
            const float4 R0 = mp[0];   // (A.re, A.im, B.re, B.im)
            const float4 R1 = mp[1];   // (C.re, C.im, D.re, D.im)
            #pragma unroll
            for (int t = 0; t < NSLOT / 2; ++t) {
                const int j  = ((t >> w) << (w + 1)) | (t & ((1 << w) - 1));
                const int j2 = j | (1 << w);
                const float2 x = e[j], y = e[j2];
                e[j]  = make_float2(R0.x * x.x - R0.y * x.y + R0.z * y.x - R0.w * y.y,
                                    R0.x * x.y + R0.y * x.x + R0.z * y.y + R0.w * y.x);
                e[j2] = make_float2(R1.x * x.x - R1.y * x.y + R1.z * y.x - R1.w * y.y,
                                    R1.x * x.y + R1.y * x.x + R1.z * y.y + R1.w * y.x);
            }
        }
        #pragma unroll
        for (int j = 0; j < NSLOT; ++j) st[repf ^ pm.lut[j]] = e[j];
    }
}

__global__ __launch_bounds__(NT, 2)   // min 2 waves/EU => 256-VGPR budget cap;
                                      // LDS caps occupancy at 1 block/CU anyway
void qsim_kernel(const float* __restrict__ z, const float* __restrict__ th,
                 float* __restrict__ out)
{
    extern __shared__ float2 st[];            // 16384 x 8 B state
    __shared__ float4 gm4[28 * 4];            // [gate 0..27][variant 0/1][2x float4]
    __shared__ float2 vtab[NQ][2];            // per-wire (encoding x layer-1) |psi_w>
    __shared__ float  red[NT / 64][NQ];

    const int bq  = blockIdx.x;
    const int tid = threadIdx.x;

    // ---- metadata: fused gate matrices + per-wire product vectors ----
    if (tid < 28) {
        const int rd = tid / 14, w = tid % 14, l = rd + 1;   // theta layers 1,2
        const float* tp = th + (l * NQ + w) * 3;
        float s0, c0, s1, c1, s2, c2;
        __sincosf(0.5f * tp[0], &s0, &c0);
        __sincosf(0.5f * tp[1], &s1, &c1);
        __sincosf(0.5f * tp[2], &s2, &c2);
        const M2x2 G = mmul(mRZ(c2, s2), mmul(mRY(c1, s1), mRX(c0, s0)));
        gm4[tid * 4 + 0] = make_float4(G.a.x, G.a.y, G.b.x, G.b.y);
        gm4[tid * 4 + 1] = make_float4(G.c.x, G.c.y, G.d.x, G.d.y);
        gm4[tid * 4 + 2] = make_float4(G.d.x, G.d.y, G.c.x, G.c.y);  // swapped variant
        gm4[tid * 4 + 3] = make_float4(G.b.x, G.b.y, G.a.x, G.a.y);
    } else if (tid >= 32 && tid < 32 + NQ) {
        const int w = tid - 32;
        const float zt = z[bq * NQ + w];
        float sz_, cz_; __sincosf(0.5f * zt, &sz_, &cz_);
        // (RZ(z)*RY(z)) |0> = (cos*e^{-iz/2}, sin*e^{+iz/2})
        const c32 a0{ cz_ * cz_, -cz_ * sz_ }, b0{ sz_ * cz_, sz_ * sz_ };
        const float* tp = th + (0 * NQ + w) * 3;
        float s0, c0, s1, c1, s2, c2;
        __sincosf(0.5f * tp[0], &s0, &c0);
        __sincosf(0.5f * tp[1], &s1, &c1);
        __sincosf(0.5f * tp[2], &s2, &c2);
        const M2x2 G = mmul(mRZ(c2, s2), mmul(mRY(c1, s1), mRX(c0, s0)));
        const c32 v0 = cadd(cmul(G.a, a0), cmul(G.b, b0));
        const c32 v1 = cadd(cmul(G.c, a0), cmul(G.d, b0));
        vtab[w][0] = make_float2(v0.x, v0.y);
        vtab[w][1] = make_float2(v1.x, v1.y);
    }
    __syncthreads();

    // ---- init: product state (encoding + layer-1 folded), strided layout ----
    {
        // y = tid + j*512 ; y bit p (p<9) from tid => wire 13-p ; j bit b => wire 4-b
        float2 pf = vtab[13][tid & 1];
        #pragma unroll
        for (int p = 1; p < 9; ++p) pf = cmulf(pf, vtab[13 - p][(tid >> p) & 1]);
        // split j's bit 4 (wire 0) into the cs loop: peak live = 16 float2, not 32
        #pragma unroll
        for (int cs = 0; cs < 2; ++cs) {
            float2 e16[16];
            e16[0] = cmulf(pf, vtab[0][cs]);
            #pragma unroll
            for (int bb = 0; bb < 4; ++bb) {
                const float2 v0 = vtab[4 - bb][0], v1 = vtab[4 - bb][1];
                #pragma unroll
                for (int t = 0; t < (1 << bb); ++t) {
                    const float2 base = e16[t];
                    e16[t + (1 << bb)] = cmulf(base, v1);
                    e16[t] = cmulf(base, v0);
                }
            }
            #pragma unroll
            for (int t = 0; t < 16; ++t) st[tid + ((cs * 16 + t) << 9)] = e16[t];
        }
    }
    __syncthreads();

    // ---- 8 grouped gate passes (layers 2 and 3; K = 4,4,3,3 per layer) ----
    do_pass<0>(st, gm4, tid); __syncthreads();
    do_pass<1>(st, gm4, tid); __syncthreads();
    do_pass<2>(st, gm4, tid); __syncthreads();
    do_pass<3>(st, gm4, tid); __syncthreads();
    do_pass<4>(st, gm4, tid); __syncthreads();
    do_pass<5>(st, gm4, tid); __syncthreads();
    do_pass<6>(st, gm4, tid); __syncthreads();
    do_pass<7>(st, gm4, tid); __syncthreads();

    // ---- readout: |amp|^2, in-register WHT over the 5 high bits ----
    float W[32];
    #pragma unroll
    for (int j = 0; j < 32; ++j) {
        const float2 a = st[tid + (j << 9)];
        W[j] = a.x * a.x + a.y * a.y;
    }
    #pragma unroll
    for (int bb = 0; bb < 5; ++bb) {
        #pragma unroll
        for (int t = 0; t < 16; ++t) {
            const int j  = ((t >> bb) << (bb + 1)) | (t & ((1 << bb) - 1));
            const int j2 = j | (1 << bb);
            const float u = W[j], v = W[j2];
            W[j] = u + v; W[j2] = u - v;
        }
    }
    float ev[NQ];
    #pragma unroll
    for (int w = 0; w < NQ; ++w) {
        const float val = W[S.frow[w] >> 9];
        ev[w] = (__popc((unsigned)tid & (S.frow[w] & 0x1FFu)) & 1) ? -val : val;
    }
    const int lane = tid & 63, wv = tid >> 6;
    #pragma unroll
    for (int w = 0; w < NQ; ++w) {
        float v = ev[w];
        #pragma unroll
        for (int off = 32; off > 0; off >>= 1) v += __shfl_down(v, off, 64);
        if (lane == 0) red[wv][w] = v;
    }
    __syncthreads();
    if (tid < NQ) {
        float v = 0.f;
        #pragma unroll
        for (int i = 0; i < NT / 64; ++i) v += red[i][tid];
        out[bq * NQ + tid] = v;
    }
}

extern "C" void kernel_launch(void* const* d_in, const int* in_sizes, int n_in,
                              void* d_out, int out_size, void* d_ws, size_t ws_size,
                              hipStream_t stream)
{
    (void)n_in; (void)out_size; (void)d_ws; (void)ws_size;
    const float* z  = (const float*)d_in[0];   // (256, 14) float32
    const float* th = (const float*)d_in[1];   // (3, 14, 3) float32
    float* out = (float*)d_out;                // (256, 14) float32

    const int B = in_sizes[0] / NQ;

    hipFuncSetAttribute(reinterpret_cast<const void*>(qsim_kernel),
                        hipFuncAttributeMaxDynamicSharedMemorySize, NS * 8);

    qsim_kernel<<<dim3(B), dim3(NT), NS * 8, stream>>>(z, th, out);
}

// Round 8
// 86.491 us; speedup vs baseline: 1.6314x; 1.2463x over previous
//
#include <hip/hip_runtime.h>

// Batched 14-qubit statevector simulator, v5.
// v4 -> v5:
//  (1) Residual spill fix: v4 still wrote ~11.4 MB/dispatch of scratch
//      (68 B/thread) because fully-unrolled NCS=4 coset loops interleaved
//      4 iterations' live ranges. All cs loops are now `#pragma unroll 1`
//      so peak live = one iteration (~70 regs), below any allocator budget.
//  (2) Packed-FP32 gate math: amplitudes are <2 x float> ext-vectors and
//      gate coefficients are stored pre-swizzled (RE=(P,Q,R,S),
//      IM=(-P.im,P.im,...)) so each butterfly pair is 8 packed mul/fma
//      (v_pk_*_f32) instead of 16 scalar ops.
// - State (2^14 complex64 = 128 KB) lives in LDS per block (1 sample/block).
// - Encoding + layer-1 1q gates folded into a product state built in registers.
// - Layers 2/3: gates grouped K=4,4,3,3 per pass, cosets in registers.
// - CNOTs are compile-time GF(2) index algebra (zero data movement).
// - Readout via in-register 32-point Walsh-Hadamard transform.

#define NQ 14
#define NS (1 << NQ)
#define NT 512
#define NLAYERS 3

typedef float c2 __attribute__((ext_vector_type(2)));

// ---------------- compile-time GF(2) schedule ----------------
struct Sched {
    unsigned m2[NQ], r2[NQ];   // masks/rows for layer-2 gates (after 1 CNOT ring)
    unsigned m3[NQ], r3[NQ];   // for layer-3 gates (after 2 rings)
    unsigned frow[NQ];         // readout rows (after 3 rings)
};

constexpr Sched make_sched() {
    Sched s{};
    unsigned c[NQ] = {}, r[NQ] = {};
    for (int w = 0; w < NQ; ++w) { c[w] = 1u << (NQ - 1 - w); r[w] = 1u << (NQ - 1 - w); }
    for (int ring = 0; ring < 3; ++ring) {
        // CNOT(w, w+1) for w=0..12, then CNOT(13, 0): cols[c]^=cols[t]; rows[t]^=rows[c]
        for (int w = 0; w < NQ - 1; ++w) { c[w] ^= c[w + 1]; r[w + 1] ^= r[w]; }
        c[NQ - 1] ^= c[0]; r[0] ^= r[NQ - 1];
        if (ring == 0) for (int w = 0; w < NQ; ++w) { s.m2[w] = c[w]; s.r2[w] = r[w]; }
        if (ring == 1) for (int w = 0; w < NQ; ++w) { s.m3[w] = c[w]; s.r3[w] = r[w]; }
        if (ring == 2) for (int w = 0; w < NQ; ++w) { s.frow[w] = r[w]; }
    }
    return s;
}
constexpr Sched S = make_sched();

struct Meta {
    unsigned mask[4];
    unsigned row[4];
    unsigned lut[16];   // lut[j] = XOR of mask[i] over set bits i of j
    unsigned npiv;      // non-pivot bit mask (complement basis positions)
    int K;              // wires in this pass (4 or 3)
    int g0;             // base index into gate-matrix table
};

constexpr Meta mkpass(const unsigned* m, const unsigned* r, int w0, int K, int g0base) {
    Meta p{};
    p.K = K; p.g0 = g0base + w0;
    for (int i = 0; i < K; ++i) { p.mask[i] = m[w0 + i]; p.row[i] = r[w0 + i]; }
    // Gaussian elimination, preferring HIGH pivot bits (so non-pivots — the
    // per-thread rep bits — occupy low bits => good LDS bank spread).
    unsigned red[4] = {}, pivbit[4] = {}, pivs = 0;
    for (int i = 0; i < K; ++i) {
        unsigned v = p.mask[i];
        for (int j = 0; j < i; ++j) if (v & pivbit[j]) v ^= red[j];
        unsigned hb = 0;
        for (int b = 13; b >= 0; --b) if ((v >> b) & 1u) { hb = 1u << b; break; }
        red[i] = v; pivbit[i] = hb; pivs |= hb;
    }
    p.npiv = (~pivs) & 0x3FFFu;
    for (int j = 0; j < (1 << K); ++j) {
        unsigned x = 0;
        for (int i = 0; i < K; ++i) if ((j >> i) & 1) x ^= p.mask[i];
        p.lut[j] = x;
    }
    return p;
}

constexpr Meta PM[8] = {
    mkpass(S.m2, S.r2, 0, 4, 0),  mkpass(S.m2, S.r2, 4, 4, 0),
    mkpass(S.m2, S.r2, 8, 3, 0),  mkpass(S.m2, S.r2, 11, 3, 0),
    mkpass(S.m3, S.r3, 0, 4, 14), mkpass(S.m3, S.r3, 4, 4, 14),
    mkpass(S.m3, S.r3, 8, 3, 14), mkpass(S.m3, S.r3, 11, 3, 14),
};
static_assert(__builtin_popcount(PM[0].npiv) == 10, "GE failed p0");
static_assert(__builtin_popcount(PM[2].npiv) == 11, "GE failed p2");
static_assert(__builtin_popcount(PM[5].npiv) == 10, "GE failed p5");
static_assert(__builtin_popcount(PM[7].npiv) == 11, "GE failed p7");

// ---------------- complex helpers (setup only) ----------------
struct c32 { float x, y; };
__device__ __forceinline__ c32 cmul(c32 a, c32 b) {
    return c32{ a.x * b.x - a.y * b.y, a.x * b.y + a.y * b.x };
}
__device__ __forceinline__ c32 cadd(c32 a, c32 b) { return c32{ a.x + b.x, a.y + b.y }; }
__device__ __forceinline__ c2 cmulv(c2 a, c2 b) {
    return (c2){ a.x * b.x - a.y * b.y, a.x * b.y + a.y * b.x };
}

struct M2x2 { c32 a, b, c, d; };
__device__ __forceinline__ M2x2 mmul(M2x2 X, M2x2 Y) {
    M2x2 o;
    o.a = cadd(cmul(X.a, Y.a), cmul(X.b, Y.c));
    o.b = cadd(cmul(X.a, Y.b), cmul(X.b, Y.d));
    o.c = cadd(cmul(X.c, Y.a), cmul(X.d, Y.c));
    o.d = cadd(cmul(X.c, Y.b), cmul(X.d, Y.d));
    return o;
}
__device__ __forceinline__ M2x2 mRX(float c, float s) { return M2x2{ {c,0.f},{0.f,-s},{0.f,-s},{c,0.f} }; }
__device__ __forceinline__ M2x2 mRY(float c, float s) { return M2x2{ {c,0.f},{-s,0.f},{s,0.f},{c,0.f} }; }
__device__ __forceinline__ M2x2 mRZ(float c, float s) { return M2x2{ {c,-s},{0.f,0.f},{0.f,0.f},{c,s} }; }

// ---------------- one grouped gate pass ----------------
// gmv[gate][variant][3]: RE=(P.re,Q.re,R.re,S.re), IM0=(-P.im,P.im,-Q.im,Q.im),
//                        IM1=(-R.im,R.im,-S.im,S.im) for matrix [[P,Q],[R,S]].
template<int P>
__device__ __forceinline__ void do_pass(c2* st, const float4 (*gmv)[2][3], int tid) {
    constexpr Meta pm = PM[P];
    constexpr int K = pm.K;
    constexpr int NSLOT = 1 << K;         // 16 or 8
    constexpr int NCS = 1 << (5 - K);     // cosets per thread: 2 or 4

    #pragma unroll 1
    for (int cs = 0; cs < NCS; ++cs) {
        unsigned idx = (unsigned)tid + (unsigned)(cs << 9);
        // coset representative: deposit idx bits into non-pivot positions
        unsigned rep = 0;
        #pragma unroll
        for (int bb = 0; bb < 14; ++bb)
            if ((pm.npiv >> bb) & 1u)
                rep |= ((idx >> __builtin_popcount(pm.npiv & ((1u << bb) - 1))) & 1u) << bb;
        // lane-dependent offset within the coset (bank spread); linear in idx
        unsigned lt = 0;
        #pragma unroll
        for (int i = 0; i < K; ++i) lt ^= ((idx >> i) & 1u) ? pm.mask[i] : 0u;
        const unsigned repf = rep ^ lt;
        // role-parity per gate: selects normal vs swapped matrix variant
        unsigned sel[4];
        #pragma unroll
        for (int i = 0; i < K; ++i) sel[i] = __popc(repf & pm.row[i]) & 1u;

        c2 e[NSLOT];
        #pragma unroll
        for (int j = 0; j < NSLOT; ++j) e[j] = st[repf ^ pm.lut[j]];

        #pragma unroll
        for (int w = 0; w < K; ++w) {
            const float4* mp = gmv[pm.g0 + w][sel[w]];
            const float4 RE = mp[0];
            const float4 I0 = mp[1];
            const float4 I1 = mp[2];
            #pragma unroll
            for (int t = 0; t < NSLOT / 2; ++t) {
                const int j  = ((t >> w) << (w + 1)) | (t & ((1 << w) - 1));
                const int j2 = j | (1 << w);
                const c2 x = e[j], y = e[j2];
                const c2 xs = __builtin_shufflevector(x, x, 1, 0);
                const c2 ys = __builtin_shufflevector(y, y, 1, 0);
                e[j]  = x * RE.x + xs * (c2){I0.x, I0.y} + y * RE.y + ys * (c2){I0.z, I0.w};
                e[j2] = x * RE.z + xs * (c2){I1.x, I1.y} + y * RE.w + ys * (c2){I1.z, I1.w};
            }
        }
        #pragma unroll
        for (int j = 0; j < NSLOT; ++j) st[repf ^ pm.lut[j]] = e[j];
    }
}

__global__ __launch_bounds__(NT, 2)   // min 2 waves/EU; LDS caps 1 block/CU anyway
void qsim_kernel(const float* __restrict__ z, const float* __restrict__ th,
                 float* __restrict__ out)
{
    extern __shared__ c2 st[];                // 16384 x 8 B state
    __shared__ float4 gmv[28][2][3];          // pre-swizzled gate coeffs
    __shared__ c2     vtab[NQ][2];            // per-wire (encoding x layer-1) |psi_w>
    __shared__ float  red[NT / 64][NQ];

    const int bq  = blockIdx.x;
    const int tid = threadIdx.x;

    // ---- metadata: fused gate matrices + per-wire product vectors ----
    if (tid < 28) {
        const int rd = tid / 14, w = tid % 14, l = rd + 1;   // theta layers 1,2
        const float* tp = th + (l * NQ + w) * 3;
        float s0, c0, s1, c1, s2, c2_;
        __sincosf(0.5f * tp[0], &s0, &c0);
        __sincosf(0.5f * tp[1], &s1, &c1);
        __sincosf(0.5f * tp[2], &s2, &c2_);
        const M2x2 G = mmul(mRZ(c2_, s2), mmul(mRY(c1, s1), mRX(c0, s0)));
        // variant 0: [[a,b],[c,d]]
        gmv[tid][0][0] = make_float4(G.a.x, G.b.x, G.c.x, G.d.x);
        gmv[tid][0][1] = make_float4(-G.a.y, G.a.y, -G.b.y, G.b.y);
        gmv[tid][0][2] = make_float4(-G.c.y, G.c.y, -G.d.y, G.d.y);
        // variant 1 (slot roles swapped): [[d,c],[b,a]]
        gmv[tid][1][0] = make_float4(G.d.x, G.c.x, G.b.x, G.a.x);
        gmv[tid][1][1] = make_float4(-G.d.y, G.d.y, -G.c.y, G.c.y);
        gmv[tid][1][2] = make_float4(-G.b.y, G.b.y, -G.a.y, G.a.y);
    } else if (tid >= 32 && tid < 32 + NQ) {
        const int w = tid - 32;
        const float zt = z[bq * NQ + w];
        float sz_, cz_; __sincosf(0.5f * zt, &sz_, &cz_);
        // (RZ(z)*RY(z)) |0> = (cos*e^{-iz/2}, sin*e^{+iz/2})
        const c32 a0{ cz_ * cz_, -cz_ * sz_ }, b0{ sz_ * cz_, sz_ * sz_ };
        const float* tp = th + (0 * NQ + w) * 3;
        float s0, c0, s1, c1, s2, c2_;
        __sincosf(0.5f * tp[0], &s0, &c0);
        __sincosf(0.5f * tp[1], &s1, &c1);
        __sincosf(0.5f * tp[2], &s2, &c2_);
        const M2x2 G = mmul(mRZ(c2_, s2), mmul(mRY(c1, s1), mRX(c0, s0)));
        const c32 v0 = cadd(cmul(G.a, a0), cmul(G.b, b0));
        const c32 v1 = cadd(cmul(G.c, a0), cmul(G.d, b0));
        vtab[w][0] = (c2){ v0.x, v0.y };
        vtab[w][1] = (c2){ v1.x, v1.y };
    }
    __syncthreads();

    // ---- init: product state (encoding + layer-1 folded), strided layout ----
    {
        // y = tid + j*512 ; y bit p (p<9) from tid => wire 13-p ; j bit b => wire 4-b
        c2 pf = vtab[13][tid & 1];
        #pragma unroll
        for (int p = 1; p < 9; ++p) pf = cmulv(pf, vtab[13 - p][(tid >> p) & 1]);
        // split j's bit 4 (wire 0) into the cs loop: peak live = 16 c2, not 32
        #pragma unroll 1
        for (int cs = 0; cs < 2; ++cs) {
            c2 e16[16];
            e16[0] = cmulv(pf, vtab[0][cs]);
            #pragma unroll
            for (int bb = 0; bb < 4; ++bb) {
                const c2 v0 = vtab[4 - bb][0], v1 = vtab[4 - bb][1];
                #pragma unroll
                for (int t = 0; t < (1 << bb); ++t) {
                    const c2 base = e16[t];
                    e16[t + (1 << bb)] = cmulv(base, v1);
                    e16[t] = cmulv(base, v0);
                }
            }
            #pragma unroll
            for (int t = 0; t < 16; ++t) st[tid + ((cs * 16 + t) << 9)] = e16[t];
        }
    }
    __syncthreads();

    // ---- 8 grouped gate passes (layers 2 and 3; K = 4,4,3,3 per layer) ----
    do_pass<0>(st, gmv, tid); __syncthreads();
    do_pass<1>(st, gmv, tid); __syncthreads();
    do_pass<2>(st, gmv, tid); __syncthreads();
    do_pass<3>(st, gmv, tid); __syncthreads();
    do_pass<4>(st, gmv, tid); __syncthreads();
    do_pass<5>(st, gmv, tid); __syncthreads();
    do_pass<6>(st, gmv, tid); __syncthreads();
    do_pass<7>(st, gmv, tid); __syncthreads();

    // ---- readout: |amp|^2, in-register WHT over the 5 high bits ----
    float W[32];
    #pragma unroll
    for (int j = 0; j < 32; ++j) {
        const c2 a = st[tid + (j << 9)];
        W[j] = a.x * a.x + a.y * a.y;
    }
    #pragma unroll
    for (int bb = 0; bb < 5; ++bb) {
        #pragma unroll
        for (int t = 0; t < 16; ++t) {
            const int j  = ((t >> bb) << (bb + 1)) | (t & ((1 << bb) - 1));
            const int j2 = j | (1 << bb);
            const float u = W[j], v = W[j2];
            W[j] = u + v; W[j2] = u - v;
        }
    }
    float ev[NQ];
    #pragma unroll
    for (int w = 0; w < NQ; ++w) {
        const float val = W[S.frow[w] >> 9];
        ev[w] = (__popc((unsigned)tid & (S.frow[w] & 0x1FFu)) & 1) ? -val : val;
    }
    const int lane = tid & 63, wv = tid >> 6;
    #pragma unroll
    for (int w = 0; w < NQ; ++w) {
        float v = ev[w];
        #pragma unroll
        for (int off = 32; off > 0; off >>= 1) v += __shfl_down(v, off, 64);
        if (lane == 0) red[wv][w] = v;
    }
    __syncthreads();
    if (tid < NQ) {
        float v = 0.f;
        #pragma unroll
        for (int i = 0; i < NT / 64; ++i) v += red[i][tid];
        out[bq * NQ + tid] = v;
    }
}

extern "C" void kernel_launch(void* const* d_in, const int* in_sizes, int n_in,
                              void* d_out, int out_size, void* d_ws, size_t ws_size,
                              hipStream_t stream)
{
    (void)n_in; (void)out_size; (void)d_ws; (void)ws_size;
    const float* z  = (const float*)d_in[0];   // (256, 14) float32
    const float* th = (const float*)d_in[1];   // (3, 14, 3) float32
    float* out = (float*)d_out;                // (256, 14) float32

    const int B = in_sizes[0] / NQ;

    hipFuncSetAttribute(reinterpret_cast<const void*>(qsim_kernel),
                        hipFuncAttributeMaxDynamicSharedMemorySize, NS * 8);

    qsim_kernel<<<dim3(B), dim3(NT), NS * 8, stream>>>(z, th, out);
}

// Round 9
// 84.525 us; speedup vs baseline: 1.6694x; 1.0233x over previous
//
#include <hip/hip_runtime.h>

// Batched 14-qubit statevector simulator, v6.
// v5 -> v6:
//  (1) NT 512 -> 1024 (16 waves/CU, 4 waves/SIMD). v5 ran 2 waves/SIMD and
//      was dependency-latency-bound (VALU 58%, LDS ~50%). Per-thread work
//      halves (16 amps); K=4 passes become single-coset. 1024-thread blocks
//      force <=128 VGPR: peak live ~55, enforced by __launch_bounds__(1024,4).
//  (2) Hoisted coset-invariant index math (bit-deposit as constexpr runs,
//      lt, sel-base once per pass; per-cs = single XOR with constexpr pos10/
//      selhi10) - removes ~600 recomputed insts/thread.
// - State (2^14 complex64 = 128 KB) lives in LDS per block (1 sample/block).
// - Encoding + layer-1 1q gates folded into a product state built in registers.
// - Layers 2/3: gates grouped K=4,4,3,3 per pass, cosets in registers,
//   packed-FP32 butterflies (v_pk_*_f32).
// - CNOTs are compile-time GF(2) index algebra (zero data movement).
// - Readout via in-register 16-point Walsh-Hadamard transform.

#define NQ 14
#define NS (1 << NQ)
#define NT 1024
#define NW (NT / 64)
#define NLAYERS 3

typedef float c2 __attribute__((ext_vector_type(2)));

// ---------------- compile-time GF(2) schedule ----------------
struct Sched {
    unsigned m2[NQ], r2[NQ];   // masks/rows for layer-2 gates (after 1 CNOT ring)
    unsigned m3[NQ], r3[NQ];   // for layer-3 gates (after 2 rings)
    unsigned frow[NQ];         // readout rows (after 3 rings)
};

constexpr Sched make_sched() {
    Sched s{};
    unsigned c[NQ] = {}, r[NQ] = {};
    for (int w = 0; w < NQ; ++w) { c[w] = 1u << (NQ - 1 - w); r[w] = 1u << (NQ - 1 - w); }
    for (int ring = 0; ring < 3; ++ring) {
        // CNOT(w, w+1) for w=0..12, then CNOT(13, 0): cols[c]^=cols[t]; rows[t]^=rows[c]
        for (int w = 0; w < NQ - 1; ++w) { c[w] ^= c[w + 1]; r[w + 1] ^= r[w]; }
        c[NQ - 1] ^= c[0]; r[0] ^= r[NQ - 1];
        if (ring == 0) for (int w = 0; w < NQ; ++w) { s.m2[w] = c[w]; s.r2[w] = r[w]; }
        if (ring == 1) for (int w = 0; w < NQ; ++w) { s.m3[w] = c[w]; s.r3[w] = r[w]; }
        if (ring == 2) for (int w = 0; w < NQ; ++w) { s.frow[w] = r[w]; }
    }
    return s;
}
constexpr Sched S = make_sched();

struct Meta {
    unsigned mask[4];
    unsigned row[4];
    unsigned lut[16];        // lut[j] = XOR of mask[i] over set bits i of j
    unsigned npiv;           // non-pivot bit mask
    unsigned run_mask[10];   // tid-bit deposit, grouped into shift-runs
    int      run_shl[10];
    int      nruns;
    int      pos10;          // deposit position of idx bit 10 (cs bit; K=3 only)
    unsigned selhi10;        // K-bit: parity((1<<pos10) & row[i])
    int K;                   // wires in this pass (4 or 3)
    int g0;                  // base index into gate-matrix table
};

constexpr Meta mkpass(const unsigned* m, const unsigned* r, int w0, int K, int g0base) {
    Meta p{};
    p.K = K; p.g0 = g0base + w0;
    for (int i = 0; i < K; ++i) { p.mask[i] = m[w0 + i]; p.row[i] = r[w0 + i]; }
    // Gaussian elimination, preferring HIGH pivot bits (non-pivots occupy
    // low bits => per-thread rep bits land in LDS bank bits).
    unsigned red[4] = {}, pivbit[4] = {}, pivs = 0;
    for (int i = 0; i < K; ++i) {
        unsigned v = p.mask[i];
        for (int j = 0; j < i; ++j) if (v & pivbit[j]) v ^= red[j];
        unsigned hb = 0;
        for (int b = 13; b >= 0; --b) if ((v >> b) & 1u) { hb = 1u << b; break; }
        red[i] = v; pivbit[i] = hb; pivs |= hb;
    }
    p.npiv = (~pivs) & 0x3FFFu;
    for (int j = 0; j < (1 << K); ++j) {
        unsigned x = 0;
        for (int i = 0; i < K; ++i) if ((j >> i) & 1) x ^= p.mask[i];
        p.lut[j] = x;
    }
    // deposit positions: k-th set bit of npiv receives idx bit k
    int pos[14] = {}; int nb = 0;
    for (int b = 0; b < 14; ++b) if ((p.npiv >> b) & 1) pos[nb++] = b;
    // tid bits 0..9 grouped into equal-shift runs
    p.nruns = 0;
    int k = 0;
    while (k < 10) {
        const int off = pos[k] - k;
        unsigned mm = 0;
        while (k < 10 && pos[k] - k == off) { mm |= 1u << k; ++k; }
        p.run_mask[p.nruns] = mm;
        p.run_shl[p.nruns] = off;
        ++p.nruns;
    }
    p.pos10 = (nb > 10) ? pos[10] : 0;
    p.selhi10 = 0;
    if (nb > 10)
        for (int i = 0; i < K; ++i)
            p.selhi10 |= ((p.row[i] >> p.pos10) & 1u) << i;
    return p;
}

constexpr Meta PM[8] = {
    mkpass(S.m2, S.r2, 0, 4, 0),  mkpass(S.m2, S.r2, 4, 4, 0),
    mkpass(S.m2, S.r2, 8, 3, 0),  mkpass(S.m2, S.r2, 11, 3, 0),
    mkpass(S.m3, S.r3, 0, 4, 14), mkpass(S.m3, S.r3, 4, 4, 14),
    mkpass(S.m3, S.r3, 8, 3, 14), mkpass(S.m3, S.r3, 11, 3, 14),
};
static_assert(__builtin_popcount(PM[0].npiv) == 10, "GE failed p0");
static_assert(__builtin_popcount(PM[2].npiv) == 11, "GE failed p2");
static_assert(__builtin_popcount(PM[5].npiv) == 10, "GE failed p5");
static_assert(__builtin_popcount(PM[7].npiv) == 11, "GE failed p7");

// ---------------- complex helpers (setup only) ----------------
struct c32 { float x, y; };
__device__ __forceinline__ c32 cmul(c32 a, c32 b) {
    return c32{ a.x * b.x - a.y * b.y, a.x * b.y + a.y * b.x };
}
__device__ __forceinline__ c32 cadd(c32 a, c32 b) { return c32{ a.x + b.x, a.y + b.y }; }
__device__ __forceinline__ c2 cmulv(c2 a, c2 b) {
    return (c2){ a.x * b.x - a.y * b.y, a.x * b.y + a.y * b.x };
}

struct M2x2 { c32 a, b, c, d; };
__device__ __forceinline__ M2x2 mmul(M2x2 X, M2x2 Y) {
    M2x2 o;
    o.a = cadd(cmul(X.a, Y.a), cmul(X.b, Y.c));
    o.b = cadd(cmul(X.a, Y.b), cmul(X.b, Y.d));
    o.c = cadd(cmul(X.c, Y.a), cmul(X.d, Y.c));
    o.d = cadd(cmul(X.c, Y.b), cmul(X.d, Y.d));
    return o;
}
__device__ __forceinline__ M2x2 mRX(float c, float s) { return M2x2{ {c,0.f},{0.f,-s},{0.f,-s},{c,0.f} }; }
__device__ __forceinline__ M2x2 mRY(float c, float s) { return M2x2{ {c,0.f},{-s,0.f},{s,0.f},{c,0.f} }; }
__device__ __forceinline__ M2x2 mRZ(float c, float s) { return M2x2{ {c,-s},{0.f,0.f},{0.f,0.f},{c,s} }; }

// ---------------- one grouped gate pass ----------------
// gmv[gate][variant][3]: RE=(P.re,Q.re,R.re,S.re), IM0=(-P.im,P.im,-Q.im,Q.im),
//                        IM1=(-R.im,R.im,-S.im,S.im) for matrix [[P,Q],[R,S]].
template<int P>
__device__ __forceinline__ void do_pass(c2* st, const float4 (*gmv)[2][3], int tid) {
    constexpr Meta pm = PM[P];
    constexpr int K = pm.K;
    constexpr int NSLOT = 1 << K;          // 16 or 8
    constexpr int NCS = (K == 4) ? 1 : 2;  // cosets per thread

    // ---- hoisted, cs-invariant index math ----
    unsigned rep = 0;
    #pragma unroll
    for (int rn = 0; rn < pm.nruns; ++rn)
        rep |= ((unsigned)tid & pm.run_mask[rn]) << pm.run_shl[rn];
    unsigned lt = 0;
    #pragma unroll
    for (int i = 0; i < K; ++i) lt ^= ((tid >> i) & 1u) ? pm.mask[i] : 0u;
    const unsigned base = rep ^ lt;        // coset rep + lane offset
    unsigned selb = 0;
    #pragma unroll
    for (int i = 0; i < K; ++i) selb |= (unsigned)(__popc(base & pm.row[i]) & 1) << i;

    #pragma unroll 1
    for (int cs = 0; cs < NCS; ++cs) {
        const unsigned repf = cs ? (base ^ (1u << pm.pos10)) : base;
        const unsigned sel  = cs ? (selb ^ pm.selhi10) : selb;

        c2 e[NSLOT];
        #pragma unroll
        for (int j = 0; j < NSLOT; ++j) e[j] = st[repf ^ pm.lut[j]];

        #pragma unroll
        for (int w = 0; w < K; ++w) {
            const float4* mp = gmv[pm.g0 + w][(sel >> w) & 1u];
            const float4 RE = mp[0];
            const float4 I0 = mp[1];
            const float4 I1 = mp[2];
            #pragma unroll
            for (int t = 0; t < NSLOT / 2; ++t) {
                const int j  = ((t >> w) << (w + 1)) | (t & ((1 << w) - 1));
                const int j2 = j | (1 << w);
                const c2 x = e[j], y = e[j2];
                const c2 xs = __builtin_shufflevector(x, x, 1, 0);
                const c2 ys = __builtin_shufflevector(y, y, 1, 0);
                e[j]  = x * RE.x + xs * (c2){I0.x, I0.y} + y * RE.y + ys * (c2){I0.z, I0.w};
                e[j2] = x * RE.z + xs * (c2){I1.x, I1.y} + y * RE.w + ys * (c2){I1.z, I1.w};
            }
        }
        #pragma unroll
        for (int j = 0; j < NSLOT; ++j) st[repf ^ pm.lut[j]] = e[j];
    }
}

__global__ __launch_bounds__(NT, 4)   // 1024 thr = 16 waves = 4 waves/EU -> 128-VGPR cap
void qsim_kernel(const float* __restrict__ z, const float* __restrict__ th,
                 float* __restrict__ out)
{
    extern __shared__ c2 st[];                // 16384 x 8 B state
    __shared__ float4 gmv[28][2][3];          // pre-swizzled gate coeffs
    __shared__ c2     vtab[NQ][2];            // per-wire (encoding x layer-1) |psi_w>
    __shared__ float  red[NW][NQ];

    const int bq  = blockIdx.x;
    const int tid = threadIdx.x;

    // ---- metadata: fused gate matrices + per-wire product vectors ----
    if (tid < 28) {
        const int rd = tid / 14, w = tid % 14, l = rd + 1;   // theta layers 1,2
        const float* tp = th + (l * NQ + w) * 3;
        float s0, c0, s1, c1, s2, c2_;
        __sincosf(0.5f * tp[0], &s0, &c0);
        __sincosf(0.5f * tp[1], &s1, &c1);
        __sincosf(0.5f * tp[2], &s2, &c2_);
        const M2x2 G = mmul(mRZ(c2_, s2), mmul(mRY(c1, s1), mRX(c0, s0)));
        // variant 0: [[a,b],[c,d]]
        gmv[tid][0][0] = make_float4(G.a.x, G.b.x, G.c.x, G.d.x);
        gmv[tid][0][1] = make_float4(-G.a.y, G.a.y, -G.b.y, G.b.y);
        gmv[tid][0][2] = make_float4(-G.c.y, G.c.y, -G.d.y, G.d.y);
        // variant 1 (slot roles swapped): [[d,c],[b,a]]
        gmv[tid][1][0] = make_float4(G.d.x, G.c.x, G.b.x, G.a.x);
        gmv[tid][1][1] = make_float4(-G.d.y, G.d.y, -G.c.y, G.c.y);
        gmv[tid][1][2] = make_float4(-G.b.y, G.b.y, -G.a.y, G.a.y);
    } else if (tid >= 32 && tid < 32 + NQ) {
        const int w = tid - 32;
        const float zt = z[bq * NQ + w];
        float sz_, cz_; __sincosf(0.5f * zt, &sz_, &cz_);
        // (RZ(z)*RY(z)) |0> = (cos*e^{-iz/2}, sin*e^{+iz/2})
        const c32 a0{ cz_ * cz_, -cz_ * sz_ }, b0{ sz_ * cz_, sz_ * sz_ };
        const float* tp = th + (0 * NQ + w) * 3;
        float s0, c0, s1, c1, s2, c2_;
        __sincosf(0.5f * tp[0], &s0, &c0);
        __sincosf(0.5f * tp[1], &s1, &c1);
        __sincosf(0.5f * tp[2], &s2, &c2_);
        const M2x2 G = mmul(mRZ(c2_, s2), mmul(mRY(c1, s1), mRX(c0, s0)));
        const c32 v0 = cadd(cmul(G.a, a0), cmul(G.b, b0));
        const c32 v1 = cadd(cmul(G.c, a0), cmul(G.d, b0));
        vtab[w][0] = (c2){ v0.x, v0.y };
        vtab[w][1] = (c2){ v1.x, v1.y };
    }
    __syncthreads();

    // ---- init: product state (encoding + layer-1 folded), strided layout ----
    {
        // y = tid + j*1024 ; y bit p (p<10) from tid => wire 13-p ; j bit b => wire 3-b
        c2 pf = vtab[13][tid & 1];
        #pragma unroll
        for (int p = 1; p < 10; ++p) pf = cmulv(pf, vtab[13 - p][(tid >> p) & 1]);
        c2 e16[16];
        e16[0] = pf;
        #pragma unroll
        for (int bb = 0; bb < 4; ++bb) {
            const c2 v0 = vtab[3 - bb][0], v1 = vtab[3 - bb][1];
            #pragma unroll
            for (int t = 0; t < (1 << bb); ++t) {
                const c2 base = e16[t];
                e16[t + (1 << bb)] = cmulv(base, v1);
                e16[t] = cmulv(base, v0);
            }
        }
        #pragma unroll
        for (int j = 0; j < 16; ++j) st[tid + (j << 10)] = e16[j];
    }
    __syncthreads();

    // ---- 8 grouped gate passes (layers 2 and 3; K = 4,4,3,3 per layer) ----
    do_pass<0>(st, gmv, tid); __syncthreads();
    do_pass<1>(st, gmv, tid); __syncthreads();
    do_pass<2>(st, gmv, tid); __syncthreads();
    do_pass<3>(st, gmv, tid); __syncthreads();
    do_pass<4>(st, gmv, tid); __syncthreads();
    do_pass<5>(st, gmv, tid); __syncthreads();
    do_pass<6>(st, gmv, tid); __syncthreads();
    do_pass<7>(st, gmv, tid); __syncthreads();

    // ---- readout: |amp|^2, in-register WHT over the 4 high bits ----
    float W[16];
    #pragma unroll
    for (int j = 0; j < 16; ++j) {
        const c2 a = st[tid + (j << 10)];
        W[j] = a.x * a.x + a.y * a.y;
    }
    #pragma unroll
    for (int bb = 0; bb < 4; ++bb) {
        #pragma unroll
        for (int t = 0; t < 8; ++t) {
            const int j  = ((t >> bb) << (bb + 1)) | (t & ((1 << bb) - 1));
            const int j2 = j | (1 << bb);
            const float u = W[j], v = W[j2];
            W[j] = u + v; W[j2] = u - v;
        }
    }
    float ev[NQ];
    #pragma unroll
    for (int w = 0; w < NQ; ++w) {
        const float val = W[S.frow[w] >> 10];
        ev[w] = (__popc((unsigned)tid & (S.frow[w] & 0x3FFu)) & 1) ? -val : val;
    }
    const int lane = tid & 63, wv = tid >> 6;
    #pragma unroll
    for (int w = 0; w < NQ; ++w) {
        float v = ev[w];
        #pragma unroll
        for (int off = 32; off > 0; off >>= 1) v += __shfl_down(v, off, 64);
        if (lane == 0) red[wv][w] = v;
    }
    __syncthreads();
    if (tid < NQ) {
        float v = 0.f;
        #pragma unroll
        for (int i = 0; i < NW; ++i) v += red[i][tid];
        out[bq * NQ + tid] = v;
    }
}

extern "C" void kernel_launch(void* const* d_in, const int* in_sizes, int n_in,
                              void* d_out, int out_size, void* d_ws, size_t ws_size,
                              hipStream_t stream)
{
    (void)n_in; (void)out_size; (void)d_ws; (void)ws_size;
    const float* z  = (const float*)d_in[0];   // (256, 14) float32
    const float* th = (const float*)d_in[1];   // (3, 14, 3) float32
    float* out = (float*)d_out;                // (256, 14) float32

    const int B = in_sizes[0] / NQ;

    hipFuncSetAttribute(reinterpret_cast<const void*>(qsim_kernel),
                        hipFuncAttributeMaxDynamicSharedMemorySize, NS * 8);

    qsim_kernel<<<dim3(B), dim3(NT), NS * 8, stream>>>(z, th, out);
}

// Round 10
// 82.484 us; speedup vs baseline: 1.7107x; 1.0247x over previous
//
#include <hip/hip_runtime.h>

// Batched 14-qubit statevector simulator, v7.
// v6 -> v7: v5/v6 showed dispatch time invariant to TLP (39.5 us at both 8
// and 16 waves/CU) with VALU ~44% and LDS ~45%: barrier-aligned phases make
// runtime the SUM of pipe bursts, not the max. So cut what the phases sum
// over: NT=512 (32 amps/thread) enables K=5,5,4 grouping -> 6 gate passes
// (was 8): LDS b64 ops/CU 4608 -> 3584, sync phases 10 -> 8. e[32] (64 VGPR)
// is now safe: v6 proved the unroll-1 + hoisted-index regime leaves peak
// live ~90 < 128 budget (VGPR_Count was 52 with e[16]).
// - State (2^14 complex64 = 128 KB) lives in LDS per block (1 sample/block).
// - Encoding + layer-1 1q gates folded into a product state built in registers.
// - Packed-FP32 butterflies (v_pk_*_f32 via <2 x float>).
// - CNOTs are compile-time GF(2) index algebra (zero data movement).
// - Readout via in-register 32-point Walsh-Hadamard transform.

#define NQ 14
#define NS (1 << NQ)
#define NT 512
#define NTB 9                  // log2(NT)
#define NW (NT / 64)
#define NLAYERS 3

typedef float c2 __attribute__((ext_vector_type(2)));

// ---------------- compile-time GF(2) schedule ----------------
struct Sched {
    unsigned m2[NQ], r2[NQ];   // masks/rows for layer-2 gates (after 1 CNOT ring)
    unsigned m3[NQ], r3[NQ];   // for layer-3 gates (after 2 rings)
    unsigned frow[NQ];         // readout rows (after 3 rings)
};

constexpr Sched make_sched() {
    Sched s{};
    unsigned c[NQ] = {}, r[NQ] = {};
    for (int w = 0; w < NQ; ++w) { c[w] = 1u << (NQ - 1 - w); r[w] = 1u << (NQ - 1 - w); }
    for (int ring = 0; ring < 3; ++ring) {
        // CNOT(w, w+1) for w=0..12, then CNOT(13, 0): cols[c]^=cols[t]; rows[t]^=rows[c]
        for (int w = 0; w < NQ - 1; ++w) { c[w] ^= c[w + 1]; r[w + 1] ^= r[w]; }
        c[NQ - 1] ^= c[0]; r[0] ^= r[NQ - 1];
        if (ring == 0) for (int w = 0; w < NQ; ++w) { s.m2[w] = c[w]; s.r2[w] = r[w]; }
        if (ring == 1) for (int w = 0; w < NQ; ++w) { s.m3[w] = c[w]; s.r3[w] = r[w]; }
        if (ring == 2) for (int w = 0; w < NQ; ++w) { s.frow[w] = r[w]; }
    }
    return s;
}
constexpr Sched S = make_sched();

struct Meta {
    unsigned mask[5];
    unsigned row[5];
    unsigned lut[32];        // lut[j] = XOR of mask[i] over set bits i of j
    unsigned npiv;           // non-pivot bit mask
    unsigned run_mask[NTB];  // tid-bit deposit, grouped into shift-runs
    int      run_shl[NTB];
    int      nruns;
    int      posC;           // deposit position of idx bit NTB (cs bit; K=4 only)
    unsigned selhiC;         // K-bit: parity((1<<posC) & row[i])
    int K;                   // wires in this pass (5 or 4)
    int g0;                  // base index into gate-matrix table
};

constexpr Meta mkpass(const unsigned* m, const unsigned* r, int w0, int K, int g0base) {
    Meta p{};
    p.K = K; p.g0 = g0base + w0;
    for (int i = 0; i < K; ++i) { p.mask[i] = m[w0 + i]; p.row[i] = r[w0 + i]; }
    // Gaussian elimination, preferring HIGH pivot bits (non-pivots occupy
    // low bits => per-thread rep bits land in LDS bank bits -> no conflicts).
    unsigned red[5] = {}, pivbit[5] = {}, pivs = 0;
    for (int i = 0; i < K; ++i) {
        unsigned v = p.mask[i];
        for (int j = 0; j < i; ++j) if (v & pivbit[j]) v ^= red[j];
        unsigned hb = 0;
        for (int b = 13; b >= 0; --b) if ((v >> b) & 1u) { hb = 1u << b; break; }
        red[i] = v; pivbit[i] = hb; pivs |= hb;
    }
    p.npiv = (~pivs) & 0x3FFFu;
    for (int j = 0; j < (1 << K); ++j) {
        unsigned x = 0;
        for (int i = 0; i < K; ++i) if ((j >> i) & 1) x ^= p.mask[i];
        p.lut[j] = x;
    }
    // deposit positions: k-th set bit of npiv receives idx bit k
    int pos[14] = {}; int nb = 0;
    for (int b = 0; b < 14; ++b) if ((p.npiv >> b) & 1) pos[nb++] = b;
    // tid bits 0..NTB-1 grouped into equal-shift runs
    p.nruns = 0;
    int k = 0;
    while (k < NTB) {
        const int off = pos[k] - k;
        unsigned mm = 0;
        while (k < NTB && pos[k] - k == off) { mm |= 1u << k; ++k; }
        p.run_mask[p.nruns] = mm;
        p.run_shl[p.nruns] = off;
        ++p.nruns;
    }
    p.posC = (nb > NTB) ? pos[NTB] : 0;
    p.selhiC = 0;
    if (nb > NTB)
        for (int i = 0; i < K; ++i)
            p.selhiC |= ((p.row[i] >> p.posC) & 1u) << i;
    return p;
}

constexpr Meta PM[6] = {
    mkpass(S.m2, S.r2, 0, 5, 0),  mkpass(S.m2, S.r2, 5, 5, 0),  mkpass(S.m2, S.r2, 10, 4, 0),
    mkpass(S.m3, S.r3, 0, 5, 14), mkpass(S.m3, S.r3, 5, 5, 14), mkpass(S.m3, S.r3, 10, 4, 14),
};
static_assert(__builtin_popcount(PM[0].npiv) == 9,  "GE failed p0");
static_assert(__builtin_popcount(PM[1].npiv) == 9,  "GE failed p1");
static_assert(__builtin_popcount(PM[2].npiv) == 10, "GE failed p2");
static_assert(__builtin_popcount(PM[3].npiv) == 9,  "GE failed p3");
static_assert(__builtin_popcount(PM[4].npiv) == 9,  "GE failed p4");
static_assert(__builtin_popcount(PM[5].npiv) == 10, "GE failed p5");

// ---------------- complex helpers (setup only) ----------------
struct c32 { float x, y; };
__device__ __forceinline__ c32 cmul(c32 a, c32 b) {
    return c32{ a.x * b.x - a.y * b.y, a.x * b.y + a.y * b.x };
}
__device__ __forceinline__ c32 cadd(c32 a, c32 b) { return c32{ a.x + b.x, a.y + b.y }; }
__device__ __forceinline__ c2 cmulv(c2 a, c2 b) {
    return (c2){ a.x * b.x - a.y * b.y, a.x * b.y + a.y * b.x };
}

struct M2x2 { c32 a, b, c, d; };
__device__ __forceinline__ M2x2 mmul(M2x2 X, M2x2 Y) {
    M2x2 o;
    o.a = cadd(cmul(X.a, Y.a), cmul(X.b, Y.c));
    o.b = cadd(cmul(X.a, Y.b), cmul(X.b, Y.d));
    o.c = cadd(cmul(X.c, Y.a), cmul(X.d, Y.c));
    o.d = cadd(cmul(X.c, Y.b), cmul(X.d, Y.d));
    return o;
}
__device__ __forceinline__ M2x2 mRX(float c, float s) { return M2x2{ {c,0.f},{0.f,-s},{0.f,-s},{c,0.f} }; }
__device__ __forceinline__ M2x2 mRY(float c, float s) { return M2x2{ {c,0.f},{-s,0.f},{s,0.f},{c,0.f} }; }
__device__ __forceinline__ M2x2 mRZ(float c, float s) { return M2x2{ {c,-s},{0.f,0.f},{0.f,0.f},{c,s} }; }

// ---------------- one grouped gate pass ----------------
// gmv[gate][variant][3]: RE=(P.re,Q.re,R.re,S.re), IM0=(-P.im,P.im,-Q.im,Q.im),
//                        IM1=(-R.im,R.im,-S.im,S.im) for matrix [[P,Q],[R,S]].
template<int P>
__device__ __forceinline__ void do_pass(c2* st, const float4 (*gmv)[2][3], int tid) {
    constexpr Meta pm = PM[P];
    constexpr int K = pm.K;
    constexpr int NSLOT = 1 << K;          // 32 or 16
    constexpr int NCS = (K == 5) ? 1 : 2;  // cosets per thread

    // ---- hoisted, cs-invariant index math ----
    unsigned rep = 0;
    #pragma unroll
    for (int rn = 0; rn < pm.nruns; ++rn)
        rep |= ((unsigned)tid & pm.run_mask[rn]) << pm.run_shl[rn];
    unsigned lt = 0;
    #pragma unroll
    for (int i = 0; i < K; ++i) lt ^= ((tid >> i) & 1u) ? pm.mask[i] : 0u;
    const unsigned base = rep ^ lt;        // coset rep + lane offset
    unsigned selb = 0;
    #pragma unroll
    for (int i = 0; i < K; ++i) selb |= (unsigned)(__popc(base & pm.row[i]) & 1) << i;

    #pragma unroll 1
    for (int cs = 0; cs < NCS; ++cs) {
        const unsigned repf = cs ? (base ^ (1u << pm.posC)) : base;
        const unsigned sel  = cs ? (selb ^ pm.selhiC) : selb;

        c2 e[NSLOT];
        #pragma unroll
        for (int j = 0; j < NSLOT; ++j) e[j] = st[repf ^ pm.lut[j]];

        #pragma unroll
        for (int w = 0; w < K; ++w) {
            const float4* mp = gmv[pm.g0 + w][(sel >> w) & 1u];
            const float4 RE = mp[0];
            const float4 I0 = mp[1];
            const float4 I1 = mp[2];
            #pragma unroll
            for (int t = 0; t < NSLOT / 2; ++t) {
                const int j  = ((t >> w) << (w + 1)) | (t & ((1 << w) - 1));
                const int j2 = j | (1 << w);
                const c2 x = e[j], y = e[j2];
                const c2 xs = __builtin_shufflevector(x, x, 1, 0);
                const c2 ys = __builtin_shufflevector(y, y, 1, 0);
                e[j]  = x * RE.x + xs * (c2){I0.x, I0.y} + y * RE.y + ys * (c2){I0.z, I0.w};
                e[j2] = x * RE.z + xs * (c2){I1.x, I1.y} + y * RE.w + ys * (c2){I1.z, I1.w};
            }
        }
        #pragma unroll
        for (int j = 0; j < NSLOT; ++j) st[repf ^ pm.lut[j]] = e[j];
    }
}

__global__ __launch_bounds__(NT, 2)   // 512 thr = 8 waves = 2 waves/EU; LDS caps 1 block/CU
void qsim_kernel(const float* __restrict__ z, const float* __restrict__ th,
                 float* __restrict__ out)
{
    extern __shared__ c2 st[];                // 16384 x 8 B state
    __shared__ float4 gmv[28][2][3];          // pre-swizzled gate coeffs
    __shared__ c2     vtab[NQ][2];            // per-wire (encoding x layer-1) |psi_w>
    __shared__ float  red[NW][NQ];

    const int bq  = blockIdx.x;
    const int tid = threadIdx.x;

    // ---- metadata: fused gate matrices + per-wire product vectors ----
    if (tid < 28) {
        const int rd = tid / 14, w = tid % 14, l = rd + 1;   // theta layers 1,2
        const float* tp = th + (l * NQ + w) * 3;
        float s0, c0, s1, c1, s2, c2_;
        __sincosf(0.5f * tp[0], &s0, &c0);
        __sincosf(0.5f * tp[1], &s1, &c1);
        __sincosf(0.5f * tp[2], &s2, &c2_);
        const M2x2 G = mmul(mRZ(c2_, s2), mmul(mRY(c1, s1), mRX(c0, s0)));
        // variant 0: [[a,b],[c,d]]
        gmv[tid][0][0] = make_float4(G.a.x, G.b.x, G.c.x, G.d.x);
        gmv[tid][0][1] = make_float4(-G.a.y, G.a.y, -G.b.y, G.b.y);
        gmv[tid][0][2] = make_float4(-G.c.y, G.c.y, -G.d.y, G.d.y);
        // variant 1 (slot roles swapped): [[d,c],[b,a]]
        gmv[tid][1][0] = make_float4(G.d.x, G.c.x, G.b.x, G.a.x);
        gmv[tid][1][1] = make_float4(-G.d.y, G.d.y, -G.c.y, G.c.y);
        gmv[tid][1][2] = make_float4(-G.b.y, G.b.y, -G.a.y, G.a.y);
    } else if (tid >= 32 && tid < 32 + NQ) {
        const int w = tid - 32;
        const float zt = z[bq * NQ + w];
        float sz_, cz_; __sincosf(0.5f * zt, &sz_, &cz_);
        // (RZ(z)*RY(z)) |0> = (cos*e^{-iz/2}, sin*e^{+iz/2})
        const c32 a0{ cz_ * cz_, -cz_ * sz_ }, b0{ sz_ * cz_, sz_ * sz_ };
        const float* tp = th + (0 * NQ + w) * 3;
        float s0, c0, s1, c1, s2, c2_;
        __sincosf(0.5f * tp[0], &s0, &c0);
        __sincosf(0.5f * tp[1], &s1, &c1);
        __sincosf(0.5f * tp[2], &s2, &c2_);
        const M2x2 G = mmul(mRZ(c2_, s2), mmul(mRY(c1, s1), mRX(c0, s0)));
        const c32 v0 = cadd(cmul(G.a, a0), cmul(G.b, b0));
        const c32 v1 = cadd(cmul(G.c, a0), cmul(G.d, b0));
        vtab[w][0] = (c2){ v0.x, v0.y };
        vtab[w][1] = (c2){ v1.x, v1.y };
    }
    __syncthreads();

    // ---- init: product state (encoding + layer-1 folded), strided layout ----
    {
        // y = tid + j*512 ; y bit p (p<9) from tid => wire 13-p ; j bit b => wire 4-b
        c2 pf = vtab[13][tid & 1];
        #pragma unroll
        for (int p = 1; p < 9; ++p) pf = cmulv(pf, vtab[13 - p][(tid >> p) & 1]);
        // split j's bit 4 (wire 0) into the cs loop: peak live = 16 c2, not 32
        #pragma unroll 1
        for (int cs = 0; cs < 2; ++cs) {
            c2 e16[16];
            e16[0] = cmulv(pf, vtab[0][cs]);
            #pragma unroll
            for (int bb = 0; bb < 4; ++bb) {
                const c2 v0 = vtab[4 - bb][0], v1 = vtab[4 - bb][1];
                #pragma unroll
                for (int t = 0; t < (1 << bb); ++t) {
                    const c2 base = e16[t];
                    e16[t + (1 << bb)] = cmulv(base, v1);
                    e16[t] = cmulv(base, v0);
                }
            }
            #pragma unroll
            for (int t = 0; t < 16; ++t) st[tid + ((cs * 16 + t) << 9)] = e16[t];
        }
    }
    __syncthreads();

    // ---- 6 grouped gate passes (layers 2 and 3; K = 5,5,4 per layer) ----
    do_pass<0>(st, gmv, tid); __syncthreads();
    do_pass<1>(st, gmv, tid); __syncthreads();
    do_pass<2>(st, gmv, tid); __syncthreads();
    do_pass<3>(st, gmv, tid); __syncthreads();
    do_pass<4>(st, gmv, tid); __syncthreads();
    do_pass<5>(st, gmv, tid); __syncthreads();

    // ---- readout: |amp|^2, in-register WHT over the 5 high bits ----
    float W[32];
    #pragma unroll
    for (int j = 0; j < 32; ++j) {
        const c2 a = st[tid + (j << 9)];
        W[j] = a.x * a.x + a.y * a.y;
    }
    #pragma unroll
    for (int bb = 0; bb < 5; ++bb) {
        #pragma unroll
        for (int t = 0; t < 16; ++t) {
            const int j  = ((t >> bb) << (bb + 1)) | (t & ((1 << bb) - 1));
            const int j2 = j | (1 << bb);
            const float u = W[j], v = W[j2];
            W[j] = u + v; W[j2] = u - v;
        }
    }
    float ev[NQ];
    #pragma unroll
    for (int w = 0; w < NQ; ++w) {
        const float val = W[S.frow[w] >> 9];
        ev[w] = (__popc((unsigned)tid & (S.frow[w] & 0x1FFu)) & 1) ? -val : val;
    }
    const int lane = tid & 63, wv = tid >> 6;
    #pragma unroll
    for (int w = 0; w < NQ; ++w) {
        float v = ev[w];
        #pragma unroll
        for (int off = 32; off > 0; off >>= 1) v += __shfl_down(v, off, 64);
        if (lane == 0) red[wv][w] = v;
    }
    __syncthreads();
    if (tid < NQ) {
        float v = 0.f;
        #pragma unroll
        for (int i = 0; i < NW; ++i) v += red[i][tid];
        out[bq * NQ + tid] = v;
    }
}

extern "C" void kernel_launch(void* const* d_in, const int* in_sizes, int n_in,
                              void* d_out, int out_size, void* d_ws, size_t ws_size,
                              hipStream_t stream)
{
    (void)n_in; (void)out_size; (void)d_ws; (void)ws_size;
    const float* z  = (const float*)d_in[0];   // (256, 14) float32
    const float* th = (const float*)d_in[1];   // (3, 14, 3) float32
    float* out = (float*)d_out;                // (256, 14) float32

    const int B = in_sizes[0] / NQ;

    hipFuncSetAttribute(reinterpret_cast<const void*>(qsim_kernel),
                        hipFuncAttributeMaxDynamicSharedMemorySize, NS * 8);

    qsim_kernel<<<dim3(B), dim3(NT), NS * 8, stream>>>(z, th, out);
}

// Round 11
// 81.929 us; speedup vs baseline: 1.7222x; 1.0068x over previous
//
#include <hip/hip_runtime.h>

// Batched 14-qubit statevector simulator, v8.
// v7 -> v8 (both fixes evidence-driven from round-10 counters):
//  (1) Bank-spread correction: v7's per-lane coset offset `lt` aliased LDS
//      bank bits in some passes (hand-verified: pass1 lanes collide 8-per-
//      bank-pair). Now a constexpr greedy picks wsel[i] in span{masks} per
//      tid bit 0..5 so lane->(index mod 16) has rank 4 => exactly 4 lanes
//      per bank-pair (b64 minimum) for every state read/write. Any wsel
//      choice is CORRECT (stays in the coset); rank only affects speed.
//  (2) Forced packed math: butterflies are inline-asm v_pk_mul_f32 /
//      v_pk_fma_f32 (VOP3P), 8 ops/pair, swap folded into op_sel, signs
//      pre-baked into stored (-im,+im) broadcast pairs. Removes the
//      suspected scalarization (VALU-issue was ~2.7x the packed model).
// - State (2^14 complex64 = 128 KB) in LDS per block (1 sample/block).
// - Encoding + layer-1 folded into a register-built product state.
// - Layers 2/3: K=5,5,4 grouped passes, cosets in registers (e[32]).
// - CNOTs are compile-time GF(2) index algebra (zero data movement).
// - Readout via in-register 32-point Walsh-Hadamard transform.

#define NQ 14
#define NS (1 << NQ)
#define NT 512
#define NTB 9                  // log2(NT)
#define NW (NT / 64)
#define NLAYERS 3

typedef float c2 __attribute__((ext_vector_type(2)));

// ---------------- compile-time GF(2) schedule ----------------
struct Sched {
    unsigned m2[NQ], r2[NQ];
    unsigned m3[NQ], r3[NQ];
    unsigned frow[NQ];
};

constexpr Sched make_sched() {
    Sched s{};
    unsigned c[NQ] = {}, r[NQ] = {};
    for (int w = 0; w < NQ; ++w) { c[w] = 1u << (NQ - 1 - w); r[w] = 1u << (NQ - 1 - w); }
    for (int ring = 0; ring < 3; ++ring) {
        for (int w = 0; w < NQ - 1; ++w) { c[w] ^= c[w + 1]; r[w + 1] ^= r[w]; }
        c[NQ - 1] ^= c[0]; r[0] ^= r[NQ - 1];
        if (ring == 0) for (int w = 0; w < NQ; ++w) { s.m2[w] = c[w]; s.r2[w] = r[w]; }
        if (ring == 1) for (int w = 0; w < NQ; ++w) { s.m3[w] = c[w]; s.r3[w] = r[w]; }
        if (ring == 2) for (int w = 0; w < NQ; ++w) { s.frow[w] = r[w]; }
    }
    return s;
}
constexpr Sched S = make_sched();

struct Meta {
    unsigned mask[5];
    unsigned row[5];
    unsigned lut[32];        // lut[j] = XOR of mask[i] over set bits i of j
    unsigned npiv;
    unsigned run_mask[NTB];  // tid-bit deposit, grouped into shift-runs
    int      run_shl[NTB];
    int      nruns;
    unsigned wsel[6];        // per-lane-bit in-coset offset (bank spread)
    int      posC;           // deposit position of idx bit NTB (K=4 only)
    unsigned selhiC;
    int K;
    int g0;
};

constexpr Meta mkpass(const unsigned* m, const unsigned* r, int w0, int K, int g0base) {
    Meta p{};
    p.K = K; p.g0 = g0base + w0;
    for (int i = 0; i < K; ++i) { p.mask[i] = m[w0 + i]; p.row[i] = r[w0 + i]; }
    // GE with high-preferred pivots: non-pivot (coset-label) bits sit low.
    unsigned red[5] = {}, pivbit[5] = {}, pivs = 0;
    for (int i = 0; i < K; ++i) {
        unsigned v = p.mask[i];
        for (int j = 0; j < i; ++j) if (v & pivbit[j]) v ^= red[j];
        unsigned hb = 0;
        for (int b = 13; b >= 0; --b) if ((v >> b) & 1u) { hb = 1u << b; break; }
        red[i] = v; pivbit[i] = hb; pivs |= hb;
    }
    p.npiv = (~pivs) & 0x3FFFu;
    for (int j = 0; j < (1 << K); ++j) {
        unsigned x = 0;
        for (int i = 0; i < K; ++i) if ((j >> i) & 1) x ^= p.mask[i];
        p.lut[j] = x;
    }
    int pos[14] = {}; int nb = 0;
    for (int b = 0; b < 14; ++b) if ((p.npiv >> b) & 1) pos[nb++] = b;
    p.nruns = 0;
    int k = 0;
    while (k < NTB) {
        const int off = pos[k] - k;
        unsigned mm = 0;
        while (k < NTB && pos[k] - k == off) { mm |= 1u << k; ++k; }
        p.run_mask[p.nruns] = mm;
        p.run_shl[p.nruns] = off;
        ++p.nruns;
    }
    p.posC = (nb > NTB) ? pos[NTB] : 0;
    p.selhiC = 0;
    if (nb > NTB)
        for (int i = 0; i < K; ++i)
            p.selhiC |= ((p.row[i] >> p.posC) & 1u) << i;
    // ---- bank-spread: choose wsel[i] (i = lane tid bit 0..5) in span{masks}
    // so that columns (depcol_i ^ wsel_i) & 15 reach rank 4 (4 lanes/bank-pair).
    {
        unsigned basis[4] = {}; int nb2 = 0;
        for (int i = 0; i < 6; ++i) {
            p.wsel[i] = 0;
            bool done = false;
            for (int j = 0; j < (1 << K) && !done; ++j) {
                unsigned v = ((1u << pos[i]) ^ p.lut[j]) & 15u;
                for (int b = 0; b < nb2; ++b) {
                    unsigned hb = 0;
                    for (int t = 3; t >= 0; --t) if ((basis[b] >> t) & 1u) { hb = 1u << t; break; }
                    if (v & hb) v ^= basis[b];
                }
                if (v != 0) { basis[nb2++] = v; p.wsel[i] = p.lut[j]; done = true; }
            }
            if (nb2 == 4) break;
        }
    }
    return p;
}

constexpr Meta PM[6] = {
    mkpass(S.m2, S.r2, 0, 5, 0),  mkpass(S.m2, S.r2, 5, 5, 0),  mkpass(S.m2, S.r2, 10, 4, 0),
    mkpass(S.m3, S.r3, 0, 5, 14), mkpass(S.m3, S.r3, 5, 5, 14), mkpass(S.m3, S.r3, 10, 4, 14),
};
static_assert(__builtin_popcount(PM[0].npiv) == 9,  "GE failed p0");
static_assert(__builtin_popcount(PM[2].npiv) == 10, "GE failed p2");
static_assert(__builtin_popcount(PM[5].npiv) == 10, "GE failed p5");

// ---------------- complex helpers (setup only) ----------------
struct c32 { float x, y; };
__device__ __forceinline__ c32 cmul(c32 a, c32 b) {
    return c32{ a.x * b.x - a.y * b.y, a.x * b.y + a.y * b.x };
}
__device__ __forceinline__ c32 cadd(c32 a, c32 b) { return c32{ a.x + b.x, a.y + b.y }; }
__device__ __forceinline__ c2 cmulv(c2 a, c2 b) {
    return (c2){ a.x * b.x - a.y * b.y, a.x * b.y + a.y * b.x };
}

struct M2x2 { c32 a, b, c, d; };
__device__ __forceinline__ M2x2 mmul(M2x2 X, M2x2 Y) {
    M2x2 o;
    o.a = cadd(cmul(X.a, Y.a), cmul(X.b, Y.c));
    o.b = cadd(cmul(X.a, Y.b), cmul(X.b, Y.d));
    o.c = cadd(cmul(X.c, Y.a), cmul(X.d, Y.c));
    o.d = cadd(cmul(X.c, Y.b), cmul(X.d, Y.d));
    return o;
}
__device__ __forceinline__ M2x2 mRX(float c, float s) { return M2x2{ {c,0.f},{0.f,-s},{0.f,-s},{c,0.f} }; }
__device__ __forceinline__ M2x2 mRY(float c, float s) { return M2x2{ {c,0.f},{-s,0.f},{s,0.f},{c,0.f} }; }
__device__ __forceinline__ M2x2 mRZ(float c, float s) { return M2x2{ {c,-s},{0.f,0.f},{0.f,0.f},{c,s} }; }

// ---------------- packed-FP32 primitives (VOP3P, guaranteed) ----------------
// lo/hi of c2 = (re, im). pk_fma_s reads src0 SWAPPED (lo<-hi, hi<-lo) via
// op_sel; the sign pattern for complex mul is pre-baked in the (-im,+im)
// broadcast-pair constants, so no neg modifiers are needed.
__device__ __forceinline__ c2 pk_mul(c2 a, c2 b) {
    c2 d; asm("v_pk_mul_f32 %0, %1, %2" : "=v"(d) : "v"(a), "v"(b)); return d;
}
__device__ __forceinline__ c2 pk_fma(c2 a, c2 b, c2 c) {
    c2 d; asm("v_pk_fma_f32 %0, %1, %2, %3" : "=v"(d) : "v"(a), "v"(b), "v"(c)); return d;
}
__device__ __forceinline__ c2 pk_fma_s(c2 a, c2 b, c2 c) {
    c2 d; asm("v_pk_fma_f32 %0, %1, %2, %3 op_sel:[1,0,0] op_sel_hi:[0,1,1]"
               : "=v"(d) : "v"(a), "v"(b), "v"(c)); return d;
}

// ---------------- one grouped gate pass ----------------
// gm[gate][variant][8] (c2 broadcast pairs) for matrix [[P,Q],[R,S]]:
//  [0]=(P.re,P.re) [1]=(-P.im,P.im) [2]=(Q.re,Q.re) [3]=(-Q.im,Q.im)
//  [4]=(R.re,R.re) [5]=(-R.im,R.im) [6]=(S.re,S.re) [7]=(-S.im,S.im)
template<int P>
__device__ __forceinline__ void do_pass(c2* st, const c2 (*gm)[2][8], int tid) {
    constexpr Meta pm = PM[P];
    constexpr int K = pm.K;
    constexpr int NSLOT = 1 << K;          // 32 or 16
    constexpr int NCS = (K == 5) ? 1 : 2;

    // hoisted, cs-invariant index math
    unsigned rep = 0;
    #pragma unroll
    for (int rn = 0; rn < pm.nruns; ++rn)
        rep |= ((unsigned)tid & pm.run_mask[rn]) << pm.run_shl[rn];
    unsigned corr = 0;
    #pragma unroll
    for (int i = 0; i < 6; ++i)
        if (pm.wsel[i]) corr ^= ((tid >> i) & 1u) ? pm.wsel[i] : 0u;
    const unsigned base = rep ^ corr;
    unsigned selb = 0;
    #pragma unroll
    for (int i = 0; i < K; ++i) selb |= (unsigned)(__popc(base & pm.row[i]) & 1) << i;

    #pragma unroll 1
    for (int cs = 0; cs < NCS; ++cs) {
        const unsigned repf = cs ? (base ^ (1u << pm.posC)) : base;
        const unsigned sel  = cs ? (selb ^ pm.selhiC) : selb;

        c2 e[NSLOT];
        #pragma unroll
        for (int j = 0; j < NSLOT; ++j) e[j] = st[repf ^ pm.lut[j]];

        #pragma unroll
        for (int w = 0; w < K; ++w) {
            const c2* mp = gm[pm.g0 + w][(sel >> w) & 1u];
            const c2 m0 = mp[0], m1 = mp[1], m2_ = mp[2], m3 = mp[3];
            const c2 m4 = mp[4], m5 = mp[5], m6 = mp[6], m7 = mp[7];
            #pragma unroll
            for (int t = 0; t < NSLOT / 2; ++t) {
                const int j  = ((t >> w) << (w + 1)) | (t & ((1 << w) - 1));
                const int j2 = j | (1 << w);
                const c2 x = e[j], y = e[j2];
                c2 a0 = pk_mul(x, m0);
                a0 = pk_fma_s(x, m1, a0);
                a0 = pk_fma(y, m2_, a0);
                a0 = pk_fma_s(y, m3, a0);
                c2 a1 = pk_mul(x, m4);
                a1 = pk_fma_s(x, m5, a1);
                a1 = pk_fma(y, m6, a1);
                a1 = pk_fma_s(y, m7, a1);
                e[j] = a0; e[j2] = a1;
            }
        }
        #pragma unroll
        for (int j = 0; j < NSLOT; ++j) st[repf ^ pm.lut[j]] = e[j];
    }
}

__global__ __launch_bounds__(NT, 2)
void qsim_kernel(const float* __restrict__ z, const float* __restrict__ th,
                 float* __restrict__ out)
{
    extern __shared__ c2 st[];                // 16384 x 8 B state
    __shared__ c2    gm[28][2][8];            // broadcast-pair gate coeffs
    __shared__ c2    vtab[NQ][2];
    __shared__ float red[NW][NQ];

    const int bq  = blockIdx.x;
    const int tid = threadIdx.x;

    // ---- metadata: fused gate matrices + per-wire product vectors ----
    if (tid < 28) {
        const int rd = tid / 14, w = tid % 14, l = rd + 1;
        const float* tp = th + (l * NQ + w) * 3;
        float s0, c0, s1, c1, s2, c2_;
        __sincosf(0.5f * tp[0], &s0, &c0);
        __sincosf(0.5f * tp[1], &s1, &c1);
        __sincosf(0.5f * tp[2], &s2, &c2_);
        const M2x2 G = mmul(mRZ(c2_, s2), mmul(mRY(c1, s1), mRX(c0, s0)));
        // variant 0: [[a,b],[c,d]] ; variant 1 (roles swapped): [[d,c],[b,a]]
        const c32 V[2][4] = { { G.a, G.b, G.c, G.d }, { G.d, G.c, G.b, G.a } };
        #pragma unroll
        for (int v = 0; v < 2; ++v) {
            #pragma unroll
            for (int q = 0; q < 4; ++q) {
                gm[tid][v][2 * q]     = (c2){ V[v][q].x,  V[v][q].x };
                gm[tid][v][2 * q + 1] = (c2){ -V[v][q].y, V[v][q].y };
            }
        }
    } else if (tid >= 32 && tid < 32 + NQ) {
        const int w = tid - 32;
        const float zt = z[bq * NQ + w];
        float sz_, cz_; __sincosf(0.5f * zt, &sz_, &cz_);
        const c32 a0{ cz_ * cz_, -cz_ * sz_ }, b0{ sz_ * cz_, sz_ * sz_ };
        const float* tp = th + (0 * NQ + w) * 3;
        float s0, c0, s1, c1, s2, c2_;
        __sincosf(0.5f * tp[0], &s0, &c0);
        __sincosf(0.5f * tp[1], &s1, &c1);
        __sincosf(0.5f * tp[2], &s2, &c2_);
        const M2x2 G = mmul(mRZ(c2_, s2), mmul(mRY(c1, s1), mRX(c0, s0)));
        const c32 v0 = cadd(cmul(G.a, a0), cmul(G.b, b0));
        const c32 v1 = cadd(cmul(G.c, a0), cmul(G.d, b0));
        vtab[w][0] = (c2){ v0.x, v0.y };
        vtab[w][1] = (c2){ v1.x, v1.y };
    }
    __syncthreads();

    // ---- init: product state (encoding + layer-1 folded), strided layout ----
    {
        c2 pf = vtab[13][tid & 1];
        #pragma unroll
        for (int p = 1; p < 9; ++p) pf = cmulv(pf, vtab[13 - p][(tid >> p) & 1]);
        #pragma unroll 1
        for (int cs = 0; cs < 2; ++cs) {
            c2 e16[16];
            e16[0] = cmulv(pf, vtab[0][cs]);
            #pragma unroll
            for (int bb = 0; bb < 4; ++bb) {
                const c2 v0 = vtab[4 - bb][0], v1 = vtab[4 - bb][1];
                #pragma unroll
                for (int t = 0; t < (1 << bb); ++t) {
                    const c2 base = e16[t];
                    e16[t + (1 << bb)] = cmulv(base, v1);
                    e16[t] = cmulv(base, v0);
                }
            }
            #pragma unroll
            for (int t = 0; t < 16; ++t) st[tid + ((cs * 16 + t) << 9)] = e16[t];
        }
    }
    __syncthreads();

    // ---- 6 grouped gate passes (layers 2 and 3; K = 5,5,4 per layer) ----
    do_pass<0>(st, gm, tid); __syncthreads();
    do_pass<1>(st, gm, tid); __syncthreads();
    do_pass<2>(st, gm, tid); __syncthreads();
    do_pass<3>(st, gm, tid); __syncthreads();
    do_pass<4>(st, gm, tid); __syncthreads();
    do_pass<5>(st, gm, tid); __syncthreads();

    // ---- readout: |amp|^2, in-register WHT over the 5 high bits ----
    float W[32];
    #pragma unroll
    for (int j = 0; j < 32; ++j) {
        const c2 a = st[tid + (j << 9)];
        W[j] = a.x * a.x + a.y * a.y;
    }
    #pragma unroll
    for (int bb = 0; bb < 5; ++bb) {
        #pragma unroll
        for (int t = 0; t < 16; ++t) {
            const int j  = ((t >> bb) << (bb + 1)) | (t & ((1 << bb) - 1));
            const int j2 = j | (1 << bb);
            const float u = W[j], v = W[j2];
            W[j] = u + v; W[j2] = u - v;
        }
    }
    float ev[NQ];
    #pragma unroll
    for (int w = 0; w < NQ; ++w) {
        const float val = W[S.frow[w] >> 9];
        ev[w] = (__popc((unsigned)tid & (S.frow[w] & 0x1FFu)) & 1) ? -val : val;
    }
    const int lane = tid & 63, wv = tid >> 6;
    #pragma unroll
    for (int w = 0; w < NQ; ++w) {
        float v = ev[w];
        #pragma unroll
        for (int off = 32; off > 0; off >>= 1) v += __shfl_down(v, off, 64);
        if (lane == 0) red[wv][w] = v;
    }
    __syncthreads();
    if (tid < NQ) {
        float v = 0.f;
        #pragma unroll
        for (int i = 0; i < NW; ++i) v += red[i][tid];
        out[bq * NQ + tid] = v;
    }
}

extern "C" void kernel_launch(void* const* d_in, const int* in_sizes, int n_in,
                              void* d_out, int out_size, void* d_ws, size_t ws_size,
                              hipStream_t stream)
{
    (void)n_in; (void)out_size; (void)d_ws; (void)ws_size;
    const float* z  = (const float*)d_in[0];   // (256, 14) float32
    const float* th = (const float*)d_in[1];   // (3, 14, 3) float32
    float* out = (float*)d_out;                // (256, 14) float32

    const int B = in_sizes[0] / NQ;

    hipFuncSetAttribute(reinterpret_cast<const void*>(qsim_kernel),
                        hipFuncAttributeMaxDynamicSharedMemorySize, NS * 8);

    qsim_kernel<<<dim3(B), dim3(NT), NS * 8, stream>>>(z, th, out);
}